// Round 9
// baseline (774.932 us; speedup 1.0000x reference)
//
#include <hip/hip_runtime.h>
#include <hip/hip_bf16.h>

#define NN 512
#define TT 60
#define DFF 6
#define EE 8192
#define TN (TT*NN)
#define TCH 20          // t-chunk size
#define NCHK 3          // number of t-chunks
#define SCALEV 0.125f
#define NEGV -1.0e10f

typedef __hip_bfloat16 bf16;
using bfrag8 = __attribute__((ext_vector_type(8))) short;   // 8 bf16 (4 VGPRs)
using facc4  = __attribute__((ext_vector_type(4))) float;   // 4 f32 acc

__device__ __forceinline__ float b2f(bf16 v){ return __bfloat162float(v); }
__device__ __forceinline__ bf16 f2b(float v){ return __float2bfloat16(v); }
__device__ __forceinline__ float lk(float x){ return x >= 0.f ? x : 0.01f*x; }
__device__ __forceinline__ float sgm(float x){ return 1.f/(1.f+__expf(-x)); }

__device__ __forceinline__ float ldf(const float* p, long i){ return p[i]; }
__device__ __forceinline__ float ldf(const bf16* p, long i){ return b2f(p[i]); }
__device__ __forceinline__ void stf(float* p, long i, float v){ p[i] = v; }
__device__ __forceinline__ void stf(bf16* p, long i, float v){ p[i] = f2b(v); }

__device__ __forceinline__ float4 ld4f(const float* p){ return *(const float4*)p; }
__device__ __forceinline__ float4 ld4f(const bf16* p){
  ushort4 u = *(const ushort4*)p;
  float4 f;
  f.x = b2f(*(const bf16*)&u.x);
  f.y = b2f(*(const bf16*)&u.y);
  f.z = b2f(*(const bf16*)&u.z);
  f.w = b2f(*(const bf16*)&u.w);
  return f;
}

__device__ __forceinline__ float wsum64(float v){
  #pragma unroll
  for (int off = 32; off; off >>= 1) v += __shfl_xor(v, off, 64);
  return v;
}
__device__ __forceinline__ float wmax64(float v){
  #pragma unroll
  for (int off = 32; off; off >>= 1) v = fmaxf(v, __shfl_xor(v, off, 64));
  return v;
}

// ---------------- pack (blocks 0..96) + adjacency bitmask (block 97, LDS atomics) ----
__global__ __launch_bounds__(256) void k_pack(
  const float* __restrict__ qw, const float* __restrict__ kw,
  const float* __restrict__ qsw, const float* __restrict__ ksw,
  const float* __restrict__ vw, const float* __restrict__ vsw,
  const float* __restrict__ vb, const float* __restrict__ vsb,
  const int* __restrict__ ei, unsigned int* __restrict__ msk,
  float* __restrict__ Wall, float* __restrict__ bcV)
{
  __shared__ unsigned int lmsk[8192];
  int tid = threadIdx.x;
  if (blockIdx.x == 97) {
    for (int i = tid; i < 8192; i += 256) lmsk[i] = 0u;
    __syncthreads();
    for (int e = tid; e < EE; e += 256) {
      int u = ei[e], v = ei[EE + e];
      atomicOr(&lmsk[u*16 + (v >> 5)], 1u << (v & 31));
    }
    __syncthreads();
    for (int i = tid; i < 8192; i += 256) msk[i] = lmsk[i];
    return;
  }
  int idx = blockIdx.x*256 + tid;
  if (idx < 6*4096) {
    int which = idx >> 12, rem = idx & 4095;
    const float* s = (which==0)?qw:(which==1)?kw:(which==2)?qsw:(which==3)?ksw:(which==4)?vw:vsw;
    Wall[idx] = s[rem];
  } else if (idx < 6*4096 + 128) {
    int o = idx - 6*4096;
    bcV[o] = (o < 64) ? vb[o] : vsb[o-64];
  }
}

// ---------------- fc_in: np-exact fp32 (seq-FMA over k, bias added after) ----------------
__global__ __launch_bounds__(256) void k_fcin(
  const float* __restrict__ x, const float* __restrict__ w, const float* __restrict__ b,
  float* __restrict__ xs, float* __restrict__ resid)
{
  long idx = (long)blockIdx.x*256 + threadIdx.x;   // < TN*64
  int o = idx & 63;
  long r = idx >> 6;                // r = t*NN + n
  int t = (int)(r / NN), n = (int)(r % NN);
  const float* xr = x + ((long)n*TT + t)*DFF;
  const float* wr = w + o*DFF;
  float acc = 0.f;
  #pragma unroll
  for (int j = 0; j < DFF; ++j) acc = fmaf(xr[j], wr[j], acc);
  float h = __fadd_rn(acc, b[o]);
  xs[idx] = h;
  resid[idx] = h;
}

// ---------------- fused per-chunk projection (np-exact seq-FMA over k=0..63) ----------------
__global__ __launch_bounds__(256) void k_proj(
  const float* __restrict__ A, const float* __restrict__ Wall, const float* __restrict__ bcV,
  float* __restrict__ qkx, float* __restrict__ qkc, bf16* __restrict__ vvc)
{
  __shared__ float As[64][68];
  __shared__ float Bs[64][68];
  int rt = blockIdx.x, bcn = blockIdx.y;
  const float* B = Wall + bcn*4096;
  int tid = threadIdx.x;
  int tx = tid & 15, ty = tid >> 4;
  float acc[4][4] = {{0.f}};
  #pragma unroll
  for (int i = 0; i < 4; ++i) {
    int t = i*256 + tid;
    int m = t >> 4, kq = (t & 15)*4;
    float4 av = *(const float4*)&A[(long)(rt*64 + m)*64 + kq];
    As[kq+0][m] = av.x; As[kq+1][m] = av.y; As[kq+2][m] = av.z; As[kq+3][m] = av.w;
    float4 bv = *(const float4*)&B[(long)m*64 + kq];
    Bs[kq+0][m] = bv.x; Bs[kq+1][m] = bv.y; Bs[kq+2][m] = bv.z; Bs[kq+3][m] = bv.w;
  }
  __syncthreads();
  for (int kk = 0; kk < 64; ++kk) {
    float4 a4 = *(const float4*)&As[kk][ty*4];
    float4 b4 = *(const float4*)&Bs[kk][tx*4];
    acc[0][0] = fmaf(a4.x,b4.x,acc[0][0]); acc[0][1] = fmaf(a4.x,b4.y,acc[0][1]); acc[0][2] = fmaf(a4.x,b4.z,acc[0][2]); acc[0][3] = fmaf(a4.x,b4.w,acc[0][3]);
    acc[1][0] = fmaf(a4.y,b4.x,acc[1][0]); acc[1][1] = fmaf(a4.y,b4.y,acc[1][1]); acc[1][2] = fmaf(a4.y,b4.z,acc[1][2]); acc[1][3] = fmaf(a4.y,b4.w,acc[1][3]);
    acc[2][0] = fmaf(a4.z,b4.x,acc[2][0]); acc[2][1] = fmaf(a4.z,b4.y,acc[2][1]); acc[2][2] = fmaf(a4.z,b4.z,acc[2][2]); acc[2][3] = fmaf(a4.z,b4.w,acc[2][3]);
    acc[3][0] = fmaf(a4.w,b4.x,acc[3][0]); acc[3][1] = fmaf(a4.w,b4.y,acc[3][1]); acc[3][2] = fmaf(a4.w,b4.z,acc[3][2]); acc[3][3] = fmaf(a4.w,b4.w,acc[3][3]);
  }
  if (bcn < 4) {
    float* C = (bcn < 2) ? qkx : qkc;
    int cb = (bcn & 1)*64;
    #pragma unroll
    for (int i = 0; i < 4; ++i) {
      long ro = (long)(rt*64 + ty*4 + i)*128 + cb + tx*4;
      #pragma unroll
      for (int j = 0; j < 4; ++j) C[ro + j] = acc[i][j];
    }
  } else {
    int cb = (bcn - 4)*64;
    float bv[4];
    #pragma unroll
    for (int j = 0; j < 4; ++j) bv[j] = bcV[cb + tx*4 + j];
    #pragma unroll
    for (int i = 0; i < 4; ++i) {
      long ro = (long)(rt*64 + ty*4 + i)*128 + cb + tx*4;
      #pragma unroll
      for (int j = 0; j < 4; ++j) vvc[ro + j] = f2b(acc[i][j] + bv[j]);
    }
  }
}

// ---------------- generic projection GEMM (fp32, tolerant paths) ----------------
template<typename TA, typename TC>
__global__ __launch_bounds__(256) void k_gemm(
  const TA* __restrict__ A, const float* __restrict__ B, const float* __restrict__ bias,
  TC* __restrict__ C, int KD, int NC, int gather)
{
  __shared__ float As[64][68];
  __shared__ float Bs[64][68];
  int rt = blockIdx.x, bcn = blockIdx.y;
  int tid = threadIdx.x;
  int tx = tid & 15, ty = tid >> 4;
  float acc[4][4] = {{0.f}};
  int nch = KD >> 6;
  for (int kc = 0; kc < nch; ++kc) {
    __syncthreads();
    #pragma unroll
    for (int i = 0; i < 4; ++i) {
      int t = i*256 + tid;
      int m = t >> 4, kq = (t & 15)*4;
      long aoff;
      int r = rt*64 + m;
      if (gather) { int n2 = r / TT, t2 = r - n2*TT; aoff = ((long)t2*NN + n2)*64 + kc*64 + kq; }
      else aoff = (long)r*KD + kc*64 + kq;
      float4 av = ld4f(A + aoff);
      As[kq+0][m] = av.x; As[kq+1][m] = av.y; As[kq+2][m] = av.z; As[kq+3][m] = av.w;
      int col = bcn*64 + m;
      float4 bv = *(const float4*)&B[(long)col*KD + kc*64 + kq];
      Bs[kq+0][m] = bv.x; Bs[kq+1][m] = bv.y; Bs[kq+2][m] = bv.z; Bs[kq+3][m] = bv.w;
    }
    __syncthreads();
    #pragma unroll 8
    for (int kk = 0; kk < 64; ++kk) {
      float4 a4 = *(const float4*)&As[kk][ty*4];
      float4 b4 = *(const float4*)&Bs[kk][tx*4];
      acc[0][0] += a4.x*b4.x; acc[0][1] += a4.x*b4.y; acc[0][2] += a4.x*b4.z; acc[0][3] += a4.x*b4.w;
      acc[1][0] += a4.y*b4.x; acc[1][1] += a4.y*b4.y; acc[1][2] += a4.y*b4.z; acc[1][3] += a4.y*b4.w;
      acc[2][0] += a4.z*b4.x; acc[2][1] += a4.z*b4.y; acc[2][2] += a4.z*b4.z; acc[2][3] += a4.z*b4.w;
      acc[3][0] += a4.w*b4.x; acc[3][1] += a4.w*b4.y; acc[3][2] += a4.w*b4.z; acc[3][3] += a4.w*b4.w;
    }
  }
  float bv[4];
  #pragma unroll
  for (int j = 0; j < 4; ++j) bv[j] = bias ? bias[bcn*64 + tx*4 + j] : 0.f;
  #pragma unroll
  for (int i = 0; i < 4; ++i) {
    long ro = (long)(rt*64 + ty*4 + i)*NC + bcn*64 + tx*4;
    #pragma unroll
    for (int j = 0; j < 4; ++j) stf(C, ro + j, acc[i][j] + bv[j]);
  }
}

// ---------------- GRU recurrence: one block (192 thr) per batch row ----------------
__global__ __launch_bounds__(192) void k_gru(
  const float* __restrict__ gi, const float* __restrict__ whh, const float* __restrict__ bhh,
  bf16* __restrict__ g_out, float* __restrict__ res_out, int layer)
{
  int n = blockIdx.x;
  int tid = threadIdx.x;
  int g = tid >> 6, o = tid & 63;
  __shared__ __align__(16) float h_lds[64];
  __shared__ float ghs[3][64];
  float4 w4[16];
  #pragma unroll
  for (int k4 = 0; k4 < 16; ++k4)
    w4[k4] = *(const float4*)&whh[(long)(g*64+o)*64 + k4*4];
  float bh = bhh[g*64+o];
  float ir = 0.f, iz = 0.f, inn = 0.f;
  if (tid < 64) {
    h_lds[tid] = 0.f;
    const float* gp = gi + ((long)n*TT + 0)*192;
    ir = gp[o]; iz = gp[64+o]; inn = gp[128+o];
  }
  __syncthreads();
  const float4* h4 = (const float4*)h_lds;
  for (int t = 0; t < TT; ++t) {
    float p0 = 0.f, p1 = 0.f, p2 = 0.f, p3 = 0.f;
    #pragma unroll
    for (int k4 = 0; k4 < 16; ++k4) {
      float4 hv = h4[k4];
      p0 = fmaf(w4[k4].x, hv.x, p0);
      p1 = fmaf(w4[k4].y, hv.y, p1);
      p2 = fmaf(w4[k4].z, hv.z, p2);
      p3 = fmaf(w4[k4].w, hv.w, p3);
    }
    ghs[g][o] = bh + ((p0 + p1) + (p2 + p3));
    __syncthreads();
    if (tid < 64) {
      float r = sgm(ir + ghs[0][o]);
      float z = sgm(iz + ghs[1][o]);
      float nn2 = tanhf(inn + r*ghs[2][o]);
      float hn = (1.f - z)*nn2 + z*h_lds[o];
      h_lds[o] = hn;
      if (layer == 0) g_out[((long)t*NN + n)*64 + o] = f2b(hn);
      else if (t == TT-1) res_out[(long)n*64 + o] = lk(hn);
      if (t + 1 < TT) {
        const float* gp = gi + ((long)n*TT + t + 1)*192;
        ir = gp[o]; iz = gp[64+o]; inn = gp[128+o];
      }
    }
    __syncthreads();
  }
}

// ---------------- merged attention, XCD-swizzled 1D grid (1920 blocks) ----------------
// Round-8 structure + T14 register double-buffer on the phase-A k-tiles (both
// paths): write tile p from regs, issue p+1's global loads immediately — HBM/L2
// latency hides under the ~600-cycle score compute. Values/order unchanged.
// VGPR budget: dyn ~100, st ~116 (q-regs absent on st path); 3-wave cap ~170.
#define MULADD4(QV, KV) \
  v0 = __fadd_rn(v0, __fmul_rn((QV).x, (KV).x)); \
  v1 = __fadd_rn(v1, __fmul_rn((QV).y, (KV).y)); \
  v2 = __fadd_rn(v2, __fmul_rn((QV).z, (KV).z)); \
  v3 = __fadd_rn(v3, __fmul_rn((QV).w, (KV).w));

__global__ __launch_bounds__(256, 3) void k_attn(
  const float* __restrict__ qkx, const float* __restrict__ qkc,
  const bf16* __restrict__ vvc, const unsigned int* __restrict__ msk,
  float* __restrict__ attn_out, float* __restrict__ resid,
  float* __restrict__ resid2, int tc)
{
  __shared__ __align__(16) char smem[52288];
  int bid = blockIdx.x;
  int vid = (bid & 7)*240 + (bid >> 3);
  int lt = vid / 96;
  int rem = vid - lt*96;
  int yy = rem >> 5;
  int qt = rem & 31;
  int gt = tc*TCH + lt;
  int tid = threadIdx.x, tx = tid & 31, grp = tid >> 5;
  int qbase = grp*2;

  if (yy == 2) {
    // ================= static attention =================
    float* kc  = (float*)smem;                 // [128][68] f32 swizzled (A)
    bf16*  vTh = (bf16*)smem;                  // [64][264] bf16 (B)
    float* qtl = (float*)(smem + 34816);       // [16][68] f32 (A)
    bf16*  P   = (bf16*)(smem + 34816);        // [16][520] bf16 (B)

    float4* q4 = (float4*)qtl;    // stride 17 float4
    float4* k4 = (float4*)kc;     // stride 17 float4

    {
      int m = tid >> 4, jc = tid & 15;
      q4[m*17 + jc] = *(const float4*)(qkc + ((long)(lt*NN + qt*16 + m))*128 + jc*4);
    }

    // T14: k-chunk register double-buffer (8 float4/thread)
    float4 sreg[8];
    #pragma unroll
    for (int j = 0; j < 8; ++j) {
      int i = tid + j*256;
      int m = i >> 4, jc = i & 15;
      sreg[j] = *(const float4*)(qkc + ((long)(lt*NN + 0*128 + m))*128 + 64 + jc*4);
    }

    float S[2][16];
    for (int p = 0; p < 4; ++p) {
      __syncthreads();
      #pragma unroll
      for (int j = 0; j < 8; ++j) {
        int i = tid + j*256;
        int m = i >> 4, jc = i & 15;
        k4[m*17 + (jc ^ ((m >> 2) & 3))] = sreg[j];
      }
      if (p < 3) {
        #pragma unroll
        for (int j = 0; j < 8; ++j) {
          int i = tid + j*256;
          int m = i >> 4, jc = i & 15;
          sreg[j] = *(const float4*)(qkc + ((long)(lt*NN + (p+1)*128 + m))*128 + 64 + jc*4);
        }
      }
      __syncthreads();
      float acc00 = 0.f, acc01 = 0.f, acc02 = 0.f, acc03 = 0.f;
      float acc10 = 0.f, acc11 = 0.f, acc12 = 0.f, acc13 = 0.f;
      #pragma unroll 4
      for (int jc = 0; jc < 16; ++jc) {
        float4 q0 = q4[(qbase+0)*17 + jc];
        float4 q1 = q4[(qbase+1)*17 + jc];
        float4 kv;
        int m0 = tx;
        kv = k4[m0*17 + (jc ^ ((m0 >> 2) & 3))];
        acc00 += q0.x*kv.x + q0.y*kv.y + q0.z*kv.z + q0.w*kv.w;
        acc10 += q1.x*kv.x + q1.y*kv.y + q1.z*kv.z + q1.w*kv.w;
        int m1 = tx + 32;
        kv = k4[m1*17 + (jc ^ ((m1 >> 2) & 3))];
        acc01 += q0.x*kv.x + q0.y*kv.y + q0.z*kv.z + q0.w*kv.w;
        acc11 += q1.x*kv.x + q1.y*kv.y + q1.z*kv.z + q1.w*kv.w;
        int m2 = tx + 64;
        kv = k4[m2*17 + (jc ^ ((m2 >> 2) & 3))];
        acc02 += q0.x*kv.x + q0.y*kv.y + q0.z*kv.z + q0.w*kv.w;
        acc12 += q1.x*kv.x + q1.y*kv.y + q1.z*kv.z + q1.w*kv.w;
        int m3 = tx + 96;
        kv = k4[m3*17 + (jc ^ ((m3 >> 2) & 3))];
        acc03 += q0.x*kv.x + q0.y*kv.y + q0.z*kv.z + q0.w*kv.w;
        acc13 += q1.x*kv.x + q1.y*kv.y + q1.z*kv.z + q1.w*kv.w;
      }
      S[0][p*4+0] = acc00; S[0][p*4+1] = acc01; S[0][p*4+2] = acc02; S[0][p*4+3] = acc03;
      S[1][p*4+0] = acc10; S[1][p*4+1] = acc11; S[1][p*4+2] = acc12; S[1][p*4+3] = acc13;
    }
    __syncthreads();   // kc + qtl dead

    #pragma unroll
    for (int qi = 0; qi < 2; ++qi) {
      #pragma unroll
      for (int ig = 0; ig < 16; ++ig) S[qi][ig] *= SCALEV;
      float lm = -INFINITY;
      #pragma unroll
      for (int ig = 0; ig < 16; ++ig) {
        bool keep = ((msk[(qt*16 + qbase + qi)*16 + ig] >> tx) & 1u) != 0u;
        float v = keep ? S[qi][ig] : NEGV;
        S[qi][ig] = v;
        lm = fmaxf(lm, v);
      }
      #pragma unroll
      for (int mk = 1; mk < 32; mk <<= 1) lm = fmaxf(lm, __shfl_xor(lm, mk, 64));
      float se = 0.f;
      #pragma unroll
      for (int ig = 0; ig < 16; ++ig) {
        float ev = __expf(S[qi][ig] - lm);
        S[qi][ig] = ev;
        se += ev;
      }
      #pragma unroll
      for (int mk = 1; mk < 32; mk <<= 1) se += __shfl_xor(se, mk, 64);
      float inv = 1.f / se;
      bf16* prow = P + (qbase + qi)*520;
      #pragma unroll
      for (int ig = 0; ig < 16; ++ig)
        prow[tx + 32*ig] = f2b(S[qi][ig]*inv);
    }

    int w = tid >> 6, l = tid & 63;
    int arow = l & 15, kgrp = l >> 4;
    facc4 acc = {0.f, 0.f, 0.f, 0.f};
    for (int kh = 0; kh < 2; ++kh) {
      __syncthreads();
      for (int i = tid; i < 2048; i += 256) {
        int m2 = (i & 127) << 1;
        int cc = (i >> 7) << 2;
        const bf16* gp = vvc + ((long)(lt*NN + kh*256 + m2))*128 + 64 + cc;
        ushort4 a = *(const ushort4*)(gp);
        ushort4 b = *(const ushort4*)(gp + 128);
        *(unsigned*)(vTh + (cc+0)*264 + m2) = (unsigned)a.x | ((unsigned)b.x << 16);
        *(unsigned*)(vTh + (cc+1)*264 + m2) = (unsigned)a.y | ((unsigned)b.y << 16);
        *(unsigned*)(vTh + (cc+2)*264 + m2) = (unsigned)a.z | ((unsigned)b.z << 16);
        *(unsigned*)(vTh + (cc+3)*264 + m2) = (unsigned)a.w | ((unsigned)b.w << 16);
      }
      __syncthreads();
      const bf16* pa = P + arow*520 + kh*256 + kgrp*8;
      const bf16* pb = vTh + (w*16 + arow)*264 + kgrp*8;
      #pragma unroll
      for (int ks = 0; ks < 8; ++ks) {
        bfrag8 av = *(const bfrag8*)(pa + ks*32);
        bfrag8 bv = *(const bfrag8*)(pb + ks*32);
        acc = __builtin_amdgcn_mfma_f32_16x16x32_bf16(av, bv, acc, 0, 0, 0);
      }
    }
    // sole writer of resid2 — plain stores, race-free vs dyn's resid +=
    long rb = ((long)gt*NN + qt*16)*64 + w*16 + arow;
    #pragma unroll
    for (int r = 0; r < 4; ++r) {
      int row = kgrp*4 + r;
      resid2[rb + (long)row*64] = acc[r];
    }
    return;
  }

  // ================= dynamic attention (h = yy) =================
  float* sc    = (float*)smem;                    // [16][520] (A)
  bf16*  vT    = (bf16*)smem;                     // [32][520] (B)
  float* kt    = (float*)(smem + 33280);          // [128][36] (A)
  bf16*  p_lds = (bf16*)(smem + 33280);           // [16][520] (B)
  float* red   = (float*)(smem + 49920);          // [2][272]
  float* ulds  = (float*)(smem + 51712);          // [16][8]
  float* means = (float*)(smem + 52224);          // [16]

  int h = yy;
  int qce = h*32, kce = 64 + h*32;

  float4 q0r[8], q1r[8];
  {
    const float* qp = qkx + ((long)(lt*NN + qt*16 + qbase))*128 + qce;
    #pragma unroll
    for (int j = 0; j < 8; ++j) q0r[j] = *(const float4*)(qp + j*4);
    #pragma unroll
    for (int j = 0; j < 8; ++j) q1r[j] = *(const float4*)(qp + 128 + j*4);
  }

  // T14: k-tile register double-buffer (4 float4/thread)
  float4 kreg[4];
  #pragma unroll
  for (int j = 0; j < 4; ++j) {
    int i = tid + j*256;
    int row = i >> 3, jj = (i & 7) << 2;
    kreg[j] = *(const float4*)(qkx + ((long)(lt*NN + 0*128 + row))*128 + kce + jj);
  }

  float S[2][16];
  for (int p = 0; p < 4; ++p) {
    __syncthreads();
    #pragma unroll
    for (int j = 0; j < 4; ++j) {
      int i = tid + j*256;
      int row = i >> 3, jj = (i & 7) << 2;
      *(float4*)(kt + row*36 + jj) = kreg[j];
    }
    if (p < 3) {
      #pragma unroll
      for (int j = 0; j < 4; ++j) {
        int i = tid + j*256;
        int row = i >> 3, jj = (i & 7) << 2;
        kreg[j] = *(const float4*)(qkx + ((long)(lt*NN + (p+1)*128 + row))*128 + kce + jj);
      }
    }
    __syncthreads();
    #pragma unroll
    for (int ii = 0; ii < 4; ++ii) {
      int m = tx + 32*ii;
      const float4* kr4 = (const float4*)(kt + m*36);
      float4 k0 = kr4[0], k1 = kr4[1], k2 = kr4[2], k3 = kr4[3];
      float4 k4 = kr4[4], k5 = kr4[5], k6 = kr4[6], k7 = kr4[7];
      // numpy einsum baseline-SIMD emulation: 4 lanes, sequential unfused
      // mul+add per lane over d = l, l+4, ..., l+28; SSE3 hadd tree at end.
      {
        float v0 = 0.f, v1 = 0.f, v2 = 0.f, v3 = 0.f;
        MULADD4(q0r[0], k0); MULADD4(q0r[1], k1); MULADD4(q0r[2], k2); MULADD4(q0r[3], k3);
        MULADD4(q0r[4], k4); MULADD4(q0r[5], k5); MULADD4(q0r[6], k6); MULADD4(q0r[7], k7);
        float s = __fadd_rn(__fadd_rn(v0, v1), __fadd_rn(v2, v3));
        s = s * 0.125f;
        S[0][p*4+ii] = s;
        sc[(qbase+0)*520 + p*128 + m] = s;
      }
      {
        float v0 = 0.f, v1 = 0.f, v2 = 0.f, v3 = 0.f;
        MULADD4(q1r[0], k0); MULADD4(q1r[1], k1); MULADD4(q1r[2], k2); MULADD4(q1r[3], k3);
        MULADD4(q1r[4], k4); MULADD4(q1r[5], k5); MULADD4(q1r[6], k6); MULADD4(q1r[7], k7);
        float s = __fadd_rn(__fadd_rn(v0, v1), __fadd_rn(v2, v3));
        s = s * 0.125f;
        S[1][p*4+ii] = s;
        sc[(qbase+1)*520 + p*128 + m] = s;
      }
    }
  }
  __syncthreads();

  // ---- T14 async-stage split: issue V-tile global loads NOW (into registers);
  //      HBM latency hides under the mean + softmax below. LDS writes deferred.
  ushort4 vpa[8], vpb[8];
  #pragma unroll
  for (int j = 0; j < 8; ++j) {
    int i = tid + j*256;
    int m2 = (i & 255) << 1;
    int cc = (i >> 8) << 2;
    const bf16* gp = vvc + ((long)(lt*NN + m2))*128 + qce + cc;
    vpa[j] = *(const ushort4*)(gp);
    vpb[j] = *(const ushort4*)(gp + 128);
  }

  // numpy pairwise mean: 4 base-blocks of 128, 8 strided accumulators each
  if (tid < 128) {
    int row = tid >> 3, b = (tid >> 1) & 3, hh = tid & 1;
    const float* a = sc + row*520 + b*128 + hh*4;
    float4 r4 = *(const float4*)a;
    #pragma unroll
    for (int i = 8; i < 128; i += 8) {
      float4 v = *(const float4*)(a + i);
      r4.x = __fadd_rn(r4.x, v.x); r4.y = __fadd_rn(r4.y, v.y);
      r4.z = __fadd_rn(r4.z, v.z); r4.w = __fadd_rn(r4.w, v.w);
    }
    ulds[row*8 + b*2 + hh] = __fadd_rn(__fadd_rn(r4.x, r4.y), __fadd_rn(r4.z, r4.w));
  }
  __syncthreads();
  if (tid < 16) {
    const float* ur = ulds + tid*8;
    float p0 = __fadd_rn(ur[0], ur[1]);
    float p1 = __fadd_rn(ur[2], ur[3]);
    float p2 = __fadd_rn(ur[4], ur[5]);
    float p3 = __fadd_rn(ur[6], ur[7]);
    means[tid] = __fadd_rn(__fadd_rn(p0, p1), __fadd_rn(p2, p3)) * (1.f/512.f);
  }
  __syncthreads();   // all sc reads complete — vT (aliasing sc) may be written after this

  long obase = ((long)(gt*2 + h))*NN*NN;
  #pragma unroll
  for (int qi = 0; qi < 2; ++qi) {
    float mn = means[qbase + qi];
    unsigned kmask = 0; float lm = -INFINITY;
    #pragma unroll
    for (int ig = 0; ig < 16; ++ig) {
      if (S[qi][ig] >= mn) { kmask |= (1u << ig); lm = fmaxf(lm, S[qi][ig]); }
    }
    #pragma unroll
    for (int mk = 1; mk < 32; mk <<= 1) lm = fmaxf(lm, __shfl_xor(lm, mk, 64));
    float e[16]; float se = 0.f;
    #pragma unroll
    for (int ig = 0; ig < 16; ++ig) {
      e[ig] = ((kmask >> ig) & 1u) ? __expf(S[qi][ig] - lm) : 0.f;
      se += e[ig];
    }
    #pragma unroll
    for (int mk = 1; mk < 32; mk <<= 1) se += __shfl_xor(se, mk, 64);
    float inv = 1.f/se;
    float* rowp = attn_out + obase + (long)(qt*16 + qbase + qi)*NN;
    bf16* prow = p_lds + (qbase + qi)*520;
    #pragma unroll
    for (int ig = 0; ig < 16; ++ig) {
      float pr = e[ig]*inv;
      __builtin_nontemporal_store(pr, rowp + tx + 32*ig);   // write-once output
      prow[tx + 32*ig] = f2b(pr);
    }
  }

  // write prefetched V^T registers to LDS (same pack arithmetic as round 6)
  #pragma unroll
  for (int j = 0; j < 8; ++j) {
    int i = tid + j*256;
    int m2 = (i & 255) << 1;
    int cc = (i >> 8) << 2;
    *(unsigned*)(vT + (cc+0)*520 + m2) = (unsigned)vpa[j].x | ((unsigned)vpb[j].x << 16);
    *(unsigned*)(vT + (cc+1)*520 + m2) = (unsigned)vpa[j].y | ((unsigned)vpb[j].y << 16);
    *(unsigned*)(vT + (cc+2)*520 + m2) = (unsigned)vpa[j].z | ((unsigned)vpb[j].z << 16);
    *(unsigned*)(vT + (cc+3)*520 + m2) = (unsigned)vpa[j].w | ((unsigned)vpb[j].w << 16);
  }
  __syncthreads();

  {
    int w = tid >> 6, l = tid & 63;
    int nh = w & 1, kh = w >> 1;
    int arow = l & 15, kgrp = l >> 4;
    facc4 acc = {0.f, 0.f, 0.f, 0.f};
    const bf16* pa = p_lds + arow*520 + kh*256 + kgrp*8;
    const bf16* pb = vT + (nh*16 + arow)*520 + kh*256 + kgrp*8;
    #pragma unroll
    for (int ks = 0; ks < 8; ++ks) {
      bfrag8 av = *(const bfrag8*)(pa + ks*32);
      bfrag8 bv = *(const bfrag8*)(pb + ks*32);
      acc = __builtin_amdgcn_mfma_f32_16x16x32_bf16(av, bv, acc, 0, 0, 0);
    }
    if (w >= 2) {
      #pragma unroll
      for (int r = 0; r < 4; ++r)
        red[nh*272 + (kgrp*4 + r)*17 + arow] = acc[r];
    }
    __syncthreads();
    if (w < 2) {
      // dyn heads write disjoint column ranges (h*32..h*32+31) — race-free
      long rb = ((long)gt*NN + qt*16)*64 + h*32 + nh*16 + arow;
      #pragma unroll
      for (int r = 0; r < 4; ++r) {
        int row = kgrp*4 + r;
        resid[rb + (long)row*64] += acc[r] + red[nh*272 + row*17 + arow];
      }
    }
  }
}

// ---------------- LN1 fused into MLP gemm1 (reads resid + resid2) ----------------
__global__ __launch_bounds__(256) void k_mlp1(
  const float* __restrict__ resid, const float* __restrict__ resid2,
  const float* __restrict__ g1, const float* __restrict__ b1,
  const float* __restrict__ B, const float* __restrict__ bias, float* __restrict__ C)
{
  __shared__ float As[64][68];
  __shared__ float Bs[64][68];
  int rt = blockIdx.x, bcn = blockIdx.y;
  int tid = threadIdx.x;
  int tx = tid & 15, ty = tid >> 4;
  int wave = tid >> 6, lane = tid & 63;
  for (int rr = wave; rr < 64; rr += 4) {
    long idx = ((long)rt*64 + rr)*64 + lane;
    float v = resid[idx] + resid2[idx];   // (h+dyn)+st — round-4 association
    float m = wsum64(v)*(1.f/64.f);
    float d = v - m;
    float var = wsum64(d*d)*(1.f/64.f);
    As[lane][rr] = d*rsqrtf(var + 1e-5f)*g1[lane] + b1[lane];
  }
  #pragma unroll
  for (int i = 0; i < 4; ++i) {
    int t = i*256 + tid;
    int m = t >> 4, kq = (t & 15)*4;
    float4 bv = *(const float4*)&B[(long)(bcn*64 + m)*64 + kq];
    Bs[kq+0][m] = bv.x; Bs[kq+1][m] = bv.y; Bs[kq+2][m] = bv.z; Bs[kq+3][m] = bv.w;
  }
  __syncthreads();
  float acc[4][4] = {{0.f}};
  #pragma unroll 8
  for (int kk = 0; kk < 64; ++kk) {
    float4 a4 = *(const float4*)&As[kk][ty*4];
    float4 b4 = *(const float4*)&Bs[kk][tx*4];
    acc[0][0] += a4.x*b4.x; acc[0][1] += a4.x*b4.y; acc[0][2] += a4.x*b4.z; acc[0][3] += a4.x*b4.w;
    acc[1][0] += a4.y*b4.x; acc[1][1] += a4.y*b4.y; acc[1][2] += a4.y*b4.z; acc[1][3] += a4.y*b4.w;
    acc[2][0] += a4.z*b4.x; acc[2][1] += a4.z*b4.y; acc[2][2] += a4.z*b4.z; acc[2][3] += a4.z*b4.w;
    acc[3][0] += a4.w*b4.x; acc[3][1] += a4.w*b4.y; acc[3][2] += a4.w*b4.z; acc[3][3] += a4.w*b4.w;
  }
  #pragma unroll
  for (int i = 0; i < 4; ++i) {
    long ro = (long)(rt*64 + ty*4 + i)*128 + bcn*64 + tx*4;
    #pragma unroll
    for (int j = 0; j < 4; ++j) C[ro + j] = acc[i][j] + bias[bcn*64 + tx*4 + j];
  }
}

// ---------------- LN2 + leaky + PE fused into mha in-projection (resid + resid2) ----
__global__ __launch_bounds__(256) void k_mha_in(
  const float* __restrict__ mlpo, const float* __restrict__ resid,
  const float* __restrict__ resid2,
  const float* __restrict__ g2, const float* __restrict__ b2,
  const float* __restrict__ B, const float* __restrict__ bias, bf16* __restrict__ C)
{
  __shared__ float As[64][68];
  __shared__ float Bs[64][68];
  int rt = blockIdx.x, bcn = blockIdx.y;
  int tid = threadIdx.x;
  int tx = tid & 15, ty = tid >> 4;
  int wave = tid >> 6, lane = tid & 63;
  for (int rr = wave; rr < 64; rr += 4) {
    long r = (long)rt*64 + rr;
    float rf = resid[r*64 + lane] + resid2[r*64 + lane];  // == round-4 resid
    float v = mlpo[r*64 + lane] + rf;
    float m = wsum64(v)*(1.f/64.f);
    float d = v - m;
    float var = wsum64(d*d)*(1.f/64.f);
    float y = d*rsqrtf(var + 1e-5f)*g2[lane] + b2[lane];
    y = lk(y);
    float tf = (float)(r / NN);
    float dv = __expf(-(float)(lane & ~1) * 0.14391156831212787f);
    float pe = (lane & 1) ? cosf(tf*dv) : sinf(tf*dv);
    As[lane][rr] = y + pe;
  }
  #pragma unroll
  for (int i = 0; i < 4; ++i) {
    int t = i*256 + tid;
    int m = t >> 4, kq = (t & 15)*4;
    float4 bv = *(const float4*)&B[(long)(bcn*64 + m)*64 + kq];
    Bs[kq+0][m] = bv.x; Bs[kq+1][m] = bv.y; Bs[kq+2][m] = bv.z; Bs[kq+3][m] = bv.w;
  }
  __syncthreads();
  float acc[4][4] = {{0.f}};
  #pragma unroll 8
  for (int kk = 0; kk < 64; ++kk) {
    float4 a4 = *(const float4*)&As[kk][ty*4];
    float4 b4 = *(const float4*)&Bs[kk][tx*4];
    acc[0][0] += a4.x*b4.x; acc[0][1] += a4.x*b4.y; acc[0][2] += a4.x*b4.z; acc[0][3] += a4.x*b4.w;
    acc[1][0] += a4.y*b4.x; acc[1][1] += a4.y*b4.y; acc[1][2] += a4.y*b4.z; acc[1][3] += a4.y*b4.w;
    acc[2][0] += a4.z*b4.x; acc[2][1] += a4.z*b4.y; acc[2][2] += a4.z*b4.z; acc[2][3] += a4.z*b4.w;
    acc[3][0] += a4.w*b4.x; acc[3][1] += a4.w*b4.y; acc[3][2] += a4.w*b4.z; acc[3][3] += a4.w*b4.w;
  }
  #pragma unroll
  for (int i = 0; i < 4; ++i) {
    long ro = (long)(rt*64 + ty*4 + i)*192 + bcn*64 + tx*4;
    #pragma unroll
    for (int j = 0; j < 4; ++j) C[ro + j] = f2b(acc[i][j] + bias[bcn*64 + tx*4 + j]);
  }
}

// ---------------- head ----------------
__global__ __launch_bounds__(64) void k_head(
  const bf16* __restrict__ mqkv, const float* __restrict__ rts,
  const float* __restrict__ mow, const float* __restrict__ mob,
  const float* __restrict__ xsw, const float* __restrict__ xtw, const float* __restrict__ xtb,
  const float* __restrict__ hw, const float* __restrict__ hb,
  const float* __restrict__ linw, const float* __restrict__ linb,
  float* __restrict__ out)
{
  int n = blockIdx.x, o = threadIdx.x;
  __shared__ float ps[TT];
  __shared__ float buf[64], buf2[64];
  float mq = b2f(mqkv[((long)(TT-1)*NN + n)*192 + o]);
  for (int s = 0; s < TT; ++s) {
    float v = mq * b2f(mqkv[((long)s*NN + n)*192 + 64 + o]);
    v = wsum64(v);
    if (o == 0) ps[s] = v * SCALEV;
  }
  __syncthreads();
  float x = (o < TT) ? ps[o] : -INFINITY;
  float mx = wmax64(x);
  float e = (o < TT) ? __expf(x - mx) : 0.f;
  float se = wsum64(e);
  if (o < TT) ps[o] = e / se;
  __syncthreads();
  float acc = 0.f;
  for (int s = 0; s < TT; ++s) acc += ps[s]*b2f(mqkv[((long)s*NN + n)*192 + 128 + o]);
  buf[o] = acc;
  __syncthreads();
  float acc2 = mob[o];
  for (int k = 0; k < 64; ++k) acc2 += buf[k]*mow[o*64 + k];
  float m2 = wsum64(acc2)*(1.f/64.f);
  float d2 = acc2 - m2;
  float var2 = wsum64(d2*d2)*(1.f/64.f);
  float a = d2*rsqrtf(var2 + 1e-5f);
  float rt = rts[(long)n*64 + o];
  __syncthreads();
  buf[o] = a; buf2[o] = rt;
  __syncthreads();
  float pre = xtb[o];
  for (int k = 0; k < 64; ++k) pre += buf[k]*xsw[o*64 + k] + buf2[k]*xtw[o*64 + k];
  float zg = sgm(pre);
  float u = zg*a + (1.f - zg)*rt;
  __syncthreads();
  buf[o] = u;
  __syncthreads();
  float f = hb[o];
  for (int k = 0; k < 64; ++k) f += buf[k]*hw[o*64 + k];
  f = lk(f);
  float tot = wsum64(f * linw[o]);
  if (o == 0) out[n] = tot + linb[0];
}

// =======================================================================
extern "C" void kernel_launch(void* const* d_in, const int* in_sizes, int n_in,
                              void* d_out, int out_size, void* d_ws, size_t ws_size,
                              hipStream_t stream)
{
  const float* x    = (const float*)d_in[0];
  const int*   ei   = (const int*)  d_in[1];
  const float* fcw  = (const float*)d_in[2];
  const float* fcb  = (const float*)d_in[3];
  const float* wih0 = (const float*)d_in[4];
  const float* whh0 = (const float*)d_in[5];
  const float* bih0 = (const float*)d_in[6];
  const float* bhh0 = (const float*)d_in[7];
  const float* wih1 = (const float*)d_in[8];
  const float* whh1 = (const float*)d_in[9];
  const float* bih1 = (const float*)d_in[10];
  const float* bhh1 = (const float*)d_in[11];
  const float* dmqw = (const float*)d_in[12];
  const float* dmkw = (const float*)d_in[13];
  const float* dmvw = (const float*)d_in[14];
  const float* dmvb = (const float*)d_in[15];
  const float* ssqw = (const float*)d_in[16];
  const float* sskw = (const float*)d_in[17];
  const float* ssvw = (const float*)d_in[18];
  const float* ssvb = (const float*)d_in[19];
  const float* ln1g = (const float*)d_in[20];
  const float* ln1b = (const float*)d_in[21];
  const float* ln2g = (const float*)d_in[22];
  const float* ln2b = (const float*)d_in[23];
  const float* mw1  = (const float*)d_in[24];
  const float* mb1  = (const float*)d_in[25];
  const float* mw2  = (const float*)d_in[26];
  const float* mb2  = (const float*)d_in[27];
  const float* mhw  = (const float*)d_in[28];
  const float* mhb  = (const float*)d_in[29];
  const float* mow  = (const float*)d_in[30];
  const float* mob  = (const float*)d_in[31];
  const float* gxsw = (const float*)d_in[32];
  const float* gxtw = (const float*)d_in[33];
  const float* gxtb = (const float*)d_in[34];
  const float* ghw  = (const float*)d_in[35];
  const float* ghb  = (const float*)d_in[36];
  const float* linw = (const float*)d_in[37];
  const float* linb = (const float*)d_in[38];

  // ---- workspace layout (~43.6 MB envelope) ----
  char* base = (char*)d_ws;
  float*  xs    = (float*)(base);                 // xs f32; later mlpo f32
  char*   Rb    = base + 7864320;                 // shared region (15.73 MB):
  float*  qkc   = (float*)Rb;                     //   per-chunk qs|ks f32 (5.24MB)
  bf16*   vvc   = (bf16*)(Rb + 5242880);          //   per-chunk v|vs bf16 (2.62MB)
  float*  qkx   = (float*)(Rb + 7864320);         //   per-chunk exact q|k f32 (5.24MB)
  float*  mlph  = (float*)Rb;                     //   later: mlp hidden f32
  bf16*   mqkv  = (bf16*)Rb;                      //   later: mha qkv bf16
  bf16*   g0    = (bf16*)(base + 23592960);
  float*  resid = (float*)(base + 27525120);      // h + dyn
  float*  resid2= (float*)(base + 35389440);      // static-attn contribution (7.86MB)
  float*  rts   = (float*)(base + 43253760);
  unsigned int* msk = (unsigned int*)(base + 43384832);
  float*  Wall  = (float*)(base + 43417600);      // 6*4096 f32 (q|k|qs|ks|v|vs)
  float*  bcV   = (float*)(base + 43515904);      // 128 f32
  float*  mlpo  = xs;
  float*  outb  = (float*)d_out;
  float*  attn  = outb + 512;
  // gi staged in d_out's attn region — dead before k_attn writes probs
  float*  gi    = (float*)((char*)d_out + 2048);

  k_pack<<<dim3(98), 256, 0, stream>>>(dmqw, dmkw, ssqw, sskw, dmvw, ssvw, dmvb, ssvb, ei, msk, Wall, bcV);
  k_fcin<<<dim3(TN*64/256), 256, 0, stream>>>(x, fcw, fcb, xs, resid);
  // GRU layer 0
  k_gemm<float,float><<<dim3(480, 3), 256, 0, stream>>>(xs, wih0, bih0, gi, 64, 192, 1);
  k_gru<<<dim3(NN), 192, 0, stream>>>(gi, whh0, bhh0, g0, nullptr, 0);
  // GRU layer 1
  k_gemm<bf16,float><<<dim3(480, 3), 256, 0, stream>>>(g0, wih1, bih1, gi, 64, 192, 1);
  k_gru<<<dim3(NN), 192, 0, stream>>>(gi, whh1, bhh1, nullptr, rts, 1);
  // attention in 3 t-chunks of 20 (dyn + static merged, XCD-swizzled 1D grid)
  for (int tc = 0; tc < NCHK; ++tc) {
    const float* xsc = xs + (size_t)tc*TCH*NN*64;
    k_proj<<<dim3(TCH*NN/64, 6), 256, 0, stream>>>(xsc, Wall, bcV, qkx, qkc, vvc);
    k_attn<<<dim3(1920), 256, 0, stream>>>(qkx, qkc, vvc, msk, attn, resid, resid2, tc);
  }
  // LN1+MLP1 -> MLP2 -> LN2+PE+mha-in -> head
  k_mlp1<<<dim3(480, 2), 256, 0, stream>>>(resid, resid2, ln1g, ln1b, mw1, mb1, mlph);
  k_gemm<float,float><<<dim3(480, 1), 256, 0, stream>>>(mlph, mw2, mb2, mlpo, 128, 64, 0);
  k_mha_in<<<dim3(480, 3), 256, 0, stream>>>(mlpo, resid, resid2, ln2g, ln2b, mhw, mhb, mqkv);
  k_head<<<dim3(NN), 64, 0, stream>>>(mqkv, rts, mow, mob, gxsw, gxtw, gxtb, ghw, ghb, linw, linb, outb);
}

// Round 10
// 713.600 us; speedup vs baseline: 1.0859x; 1.0859x over previous
//
#include <hip/hip_runtime.h>
#include <hip/hip_bf16.h>

#define NN 512
#define TT 60
#define DFF 6
#define EE 8192
#define TN (TT*NN)
#define TCH 20          // t-chunk size
#define NCHK 3          // number of t-chunks
#define SCALEV 0.125f
#define NEGV -1.0e10f

typedef __hip_bfloat16 bf16;
using bfrag8 = __attribute__((ext_vector_type(8))) short;   // 8 bf16 (4 VGPRs)
using facc4  = __attribute__((ext_vector_type(4))) float;   // 4 f32 acc

__device__ __forceinline__ float b2f(bf16 v){ return __bfloat162float(v); }
__device__ __forceinline__ bf16 f2b(float v){ return __float2bfloat16(v); }
__device__ __forceinline__ float lk(float x){ return x >= 0.f ? x : 0.01f*x; }
__device__ __forceinline__ float sgm(float x){ return 1.f/(1.f+__expf(-x)); }

__device__ __forceinline__ float ldf(const float* p, long i){ return p[i]; }
__device__ __forceinline__ float ldf(const bf16* p, long i){ return b2f(p[i]); }
__device__ __forceinline__ void stf(float* p, long i, float v){ p[i] = v; }
__device__ __forceinline__ void stf(bf16* p, long i, float v){ p[i] = f2b(v); }

__device__ __forceinline__ float4 ld4f(const float* p){ return *(const float4*)p; }
__device__ __forceinline__ float4 ld4f(const bf16* p){
  ushort4 u = *(const ushort4*)p;
  float4 f;
  f.x = b2f(*(const bf16*)&u.x);
  f.y = b2f(*(const bf16*)&u.y);
  f.z = b2f(*(const bf16*)&u.z);
  f.w = b2f(*(const bf16*)&u.w);
  return f;
}

__device__ __forceinline__ float wsum64(float v){
  #pragma unroll
  for (int off = 32; off; off >>= 1) v += __shfl_xor(v, off, 64);
  return v;
}
__device__ __forceinline__ float wmax64(float v){
  #pragma unroll
  for (int off = 32; off; off >>= 1) v = fmaxf(v, __shfl_xor(v, off, 64));
  return v;
}

// ---------------- pack (blocks 0..96) + adjacency bitmask (block 97, LDS atomics) ----
__global__ __launch_bounds__(256) void k_pack(
  const float* __restrict__ qw, const float* __restrict__ kw,
  const float* __restrict__ qsw, const float* __restrict__ ksw,
  const float* __restrict__ vw, const float* __restrict__ vsw,
  const float* __restrict__ vb, const float* __restrict__ vsb,
  const int* __restrict__ ei, unsigned int* __restrict__ msk,
  float* __restrict__ Wall, float* __restrict__ bcV)
{
  __shared__ unsigned int lmsk[8192];
  int tid = threadIdx.x;
  if (blockIdx.x == 97) {
    for (int i = tid; i < 8192; i += 256) lmsk[i] = 0u;
    __syncthreads();
    for (int e = tid; e < EE; e += 256) {
      int u = ei[e], v = ei[EE + e];
      atomicOr(&lmsk[u*16 + (v >> 5)], 1u << (v & 31));
    }
    __syncthreads();
    for (int i = tid; i < 8192; i += 256) msk[i] = lmsk[i];
    return;
  }
  int idx = blockIdx.x*256 + tid;
  if (idx < 6*4096) {
    int which = idx >> 12, rem = idx & 4095;
    const float* s = (which==0)?qw:(which==1)?kw:(which==2)?qsw:(which==3)?ksw:(which==4)?vw:vsw;
    Wall[idx] = s[rem];
  } else if (idx < 6*4096 + 128) {
    int o = idx - 6*4096;
    bcV[o] = (o < 64) ? vb[o] : vsb[o-64];
  }
}

// ---------------- fc_in: np-exact fp32 (seq-FMA over k, bias added after) ----------------
__global__ __launch_bounds__(256) void k_fcin(
  const float* __restrict__ x, const float* __restrict__ w, const float* __restrict__ b,
  float* __restrict__ xs, float* __restrict__ resid)
{
  long idx = (long)blockIdx.x*256 + threadIdx.x;   // < TN*64
  int o = idx & 63;
  long r = idx >> 6;                // r = t*NN + n
  int t = (int)(r / NN), n = (int)(r % NN);
  const float* xr = x + ((long)n*TT + t)*DFF;
  const float* wr = w + o*DFF;
  float acc = 0.f;
  #pragma unroll
  for (int j = 0; j < DFF; ++j) acc = fmaf(xr[j], wr[j], acc);
  float h = __fadd_rn(acc, b[o]);
  xs[idx] = h;
  resid[idx] = h;
}

// ---------------- fused per-chunk projection (np-exact seq-FMA over k=0..63) ----------------
__global__ __launch_bounds__(256) void k_proj(
  const float* __restrict__ A, const float* __restrict__ Wall, const float* __restrict__ bcV,
  float* __restrict__ qkx, float* __restrict__ qkc, bf16* __restrict__ vvc)
{
  __shared__ float As[64][68];
  __shared__ float Bs[64][68];
  int rt = blockIdx.x, bcn = blockIdx.y;
  const float* B = Wall + bcn*4096;
  int tid = threadIdx.x;
  int tx = tid & 15, ty = tid >> 4;
  float acc[4][4] = {{0.f}};
  #pragma unroll
  for (int i = 0; i < 4; ++i) {
    int t = i*256 + tid;
    int m = t >> 4, kq = (t & 15)*4;
    float4 av = *(const float4*)&A[(long)(rt*64 + m)*64 + kq];
    As[kq+0][m] = av.x; As[kq+1][m] = av.y; As[kq+2][m] = av.z; As[kq+3][m] = av.w;
    float4 bv = *(const float4*)&B[(long)m*64 + kq];
    Bs[kq+0][m] = bv.x; Bs[kq+1][m] = bv.y; Bs[kq+2][m] = bv.z; Bs[kq+3][m] = bv.w;
  }
  __syncthreads();
  for (int kk = 0; kk < 64; ++kk) {
    float4 a4 = *(const float4*)&As[kk][ty*4];
    float4 b4 = *(const float4*)&Bs[kk][tx*4];
    acc[0][0] = fmaf(a4.x,b4.x,acc[0][0]); acc[0][1] = fmaf(a4.x,b4.y,acc[0][1]); acc[0][2] = fmaf(a4.x,b4.z,acc[0][2]); acc[0][3] = fmaf(a4.x,b4.w,acc[0][3]);
    acc[1][0] = fmaf(a4.y,b4.x,acc[1][0]); acc[1][1] = fmaf(a4.y,b4.y,acc[1][1]); acc[1][2] = fmaf(a4.y,b4.z,acc[1][2]); acc[1][3] = fmaf(a4.y,b4.w,acc[1][3]);
    acc[2][0] = fmaf(a4.z,b4.x,acc[2][0]); acc[2][1] = fmaf(a4.z,b4.y,acc[2][1]); acc[2][2] = fmaf(a4.z,b4.z,acc[2][2]); acc[2][3] = fmaf(a4.z,b4.w,acc[2][3]);
    acc[3][0] = fmaf(a4.w,b4.x,acc[3][0]); acc[3][1] = fmaf(a4.w,b4.y,acc[3][1]); acc[3][2] = fmaf(a4.w,b4.z,acc[3][2]); acc[3][3] = fmaf(a4.w,b4.w,acc[3][3]);
  }
  if (bcn < 4) {
    float* C = (bcn < 2) ? qkx : qkc;
    int cb = (bcn & 1)*64;
    #pragma unroll
    for (int i = 0; i < 4; ++i) {
      long ro = (long)(rt*64 + ty*4 + i)*128 + cb + tx*4;
      #pragma unroll
      for (int j = 0; j < 4; ++j) C[ro + j] = acc[i][j];
    }
  } else {
    int cb = (bcn - 4)*64;
    float bv[4];
    #pragma unroll
    for (int j = 0; j < 4; ++j) bv[j] = bcV[cb + tx*4 + j];
    #pragma unroll
    for (int i = 0; i < 4; ++i) {
      long ro = (long)(rt*64 + ty*4 + i)*128 + cb + tx*4;
      #pragma unroll
      for (int j = 0; j < 4; ++j) vvc[ro + j] = f2b(acc[i][j] + bv[j]);
    }
  }
}

// ---------------- generic projection GEMM (fp32, tolerant paths) ----------------
template<typename TA, typename TC>
__global__ __launch_bounds__(256) void k_gemm(
  const TA* __restrict__ A, const float* __restrict__ B, const float* __restrict__ bias,
  TC* __restrict__ C, int KD, int NC, int gather)
{
  __shared__ float As[64][68];
  __shared__ float Bs[64][68];
  int rt = blockIdx.x, bcn = blockIdx.y;
  int tid = threadIdx.x;
  int tx = tid & 15, ty = tid >> 4;
  float acc[4][4] = {{0.f}};
  int nch = KD >> 6;
  for (int kc = 0; kc < nch; ++kc) {
    __syncthreads();
    #pragma unroll
    for (int i = 0; i < 4; ++i) {
      int t = i*256 + tid;
      int m = t >> 4, kq = (t & 15)*4;
      long aoff;
      int r = rt*64 + m;
      if (gather) { int n2 = r / TT, t2 = r - n2*TT; aoff = ((long)t2*NN + n2)*64 + kc*64 + kq; }
      else aoff = (long)r*KD + kc*64 + kq;
      float4 av = ld4f(A + aoff);
      As[kq+0][m] = av.x; As[kq+1][m] = av.y; As[kq+2][m] = av.z; As[kq+3][m] = av.w;
      int col = bcn*64 + m;
      float4 bv = *(const float4*)&B[(long)col*KD + kc*64 + kq];
      Bs[kq+0][m] = bv.x; Bs[kq+1][m] = bv.y; Bs[kq+2][m] = bv.z; Bs[kq+3][m] = bv.w;
    }
    __syncthreads();
    #pragma unroll 8
    for (int kk = 0; kk < 64; ++kk) {
      float4 a4 = *(const float4*)&As[kk][ty*4];
      float4 b4 = *(const float4*)&Bs[kk][tx*4];
      acc[0][0] += a4.x*b4.x; acc[0][1] += a4.x*b4.y; acc[0][2] += a4.x*b4.z; acc[0][3] += a4.x*b4.w;
      acc[1][0] += a4.y*b4.x; acc[1][1] += a4.y*b4.y; acc[1][2] += a4.y*b4.z; acc[1][3] += a4.y*b4.w;
      acc[2][0] += a4.z*b4.x; acc[2][1] += a4.z*b4.y; acc[2][2] += a4.z*b4.z; acc[2][3] += a4.z*b4.w;
      acc[3][0] += a4.w*b4.x; acc[3][1] += a4.w*b4.y; acc[3][2] += a4.w*b4.z; acc[3][3] += a4.w*b4.w;
    }
  }
  float bv[4];
  #pragma unroll
  for (int j = 0; j < 4; ++j) bv[j] = bias ? bias[bcn*64 + tx*4 + j] : 0.f;
  #pragma unroll
  for (int i = 0; i < 4; ++i) {
    long ro = (long)(rt*64 + ty*4 + i)*NC + bcn*64 + tx*4;
    #pragma unroll
    for (int j = 0; j < 4; ++j) stf(C, ro + j, acc[i][j] + bv[j]);
  }
}

// ---------------- GRU recurrence: one block (192 thr) per batch row ----------------
__global__ __launch_bounds__(192) void k_gru(
  const float* __restrict__ gi, const float* __restrict__ whh, const float* __restrict__ bhh,
  bf16* __restrict__ g_out, float* __restrict__ res_out, int layer)
{
  int n = blockIdx.x;
  int tid = threadIdx.x;
  int g = tid >> 6, o = tid & 63;
  __shared__ __align__(16) float h_lds[64];
  __shared__ float ghs[3][64];
  float4 w4[16];
  #pragma unroll
  for (int k4 = 0; k4 < 16; ++k4)
    w4[k4] = *(const float4*)&whh[(long)(g*64+o)*64 + k4*4];
  float bh = bhh[g*64+o];
  float ir = 0.f, iz = 0.f, inn = 0.f;
  if (tid < 64) {
    h_lds[tid] = 0.f;
    const float* gp = gi + ((long)n*TT + 0)*192;
    ir = gp[o]; iz = gp[64+o]; inn = gp[128+o];
  }
  __syncthreads();
  const float4* h4 = (const float4*)h_lds;
  for (int t = 0; t < TT; ++t) {
    float p0 = 0.f, p1 = 0.f, p2 = 0.f, p3 = 0.f;
    #pragma unroll
    for (int k4 = 0; k4 < 16; ++k4) {
      float4 hv = h4[k4];
      p0 = fmaf(w4[k4].x, hv.x, p0);
      p1 = fmaf(w4[k4].y, hv.y, p1);
      p2 = fmaf(w4[k4].z, hv.z, p2);
      p3 = fmaf(w4[k4].w, hv.w, p3);
    }
    ghs[g][o] = bh + ((p0 + p1) + (p2 + p3));
    __syncthreads();
    if (tid < 64) {
      float r = sgm(ir + ghs[0][o]);
      float z = sgm(iz + ghs[1][o]);
      float nn2 = tanhf(inn + r*ghs[2][o]);
      float hn = (1.f - z)*nn2 + z*h_lds[o];
      h_lds[o] = hn;
      if (layer == 0) g_out[((long)t*NN + n)*64 + o] = f2b(hn);
      else if (t == TT-1) res_out[(long)n*64 + o] = lk(hn);
      if (t + 1 < TT) {
        const float* gp = gi + ((long)n*TT + t + 1)*192;
        ir = gp[o]; iz = gp[64+o]; inn = gp[128+o];
      }
    }
    __syncthreads();
  }
}

// ---------------- merged attention, XCD-swizzled 1D grid (1920 blocks) ----------------
// Round-8 known-good structure (52288 B LDS, 3 blocks/CU, LDS mean, V-prefetch).
// NOTE (round-9 lesson): do NOT add phase-A register double-buffering here — the
// prefetched tiles' live range crosses the register-pressure peak and LLVM spills
// to scratch WITHOUT raising VGPR_Count (FETCH/WRITE_SIZE balloon instead).
#define MULADD4(QV, KV) \
  v0 = __fadd_rn(v0, __fmul_rn((QV).x, (KV).x)); \
  v1 = __fadd_rn(v1, __fmul_rn((QV).y, (KV).y)); \
  v2 = __fadd_rn(v2, __fmul_rn((QV).z, (KV).z)); \
  v3 = __fadd_rn(v3, __fmul_rn((QV).w, (KV).w));

__global__ __launch_bounds__(256, 3) void k_attn(
  const float* __restrict__ qkx, const float* __restrict__ qkc,
  const bf16* __restrict__ vvc, const unsigned int* __restrict__ msk,
  float* __restrict__ attn_out, float* __restrict__ resid,
  float* __restrict__ resid2, int tc)
{
  __shared__ __align__(16) char smem[52288];
  int bid = blockIdx.x;
  int vid = (bid & 7)*240 + (bid >> 3);
  int lt = vid / 96;
  int rem = vid - lt*96;
  int yy = rem >> 5;
  int qt = rem & 31;
  int gt = tc*TCH + lt;
  int tid = threadIdx.x, tx = tid & 31, grp = tid >> 5;
  int qbase = grp*2;

  if (yy == 2) {
    // ================= static attention =================
    float* kc  = (float*)smem;                 // [128][68] f32 swizzled (A)
    bf16*  vTh = (bf16*)smem;                  // [64][264] bf16 (B)
    float* qtl = (float*)(smem + 34816);       // [16][68] f32 (A)
    bf16*  P   = (bf16*)(smem + 34816);        // [16][520] bf16 (B)

    float4* q4 = (float4*)qtl;    // stride 17 float4
    float4* k4 = (float4*)kc;     // stride 17 float4

    {
      int m = tid >> 4, jc = tid & 15;
      q4[m*17 + jc] = *(const float4*)(qkc + ((long)(lt*NN + qt*16 + m))*128 + jc*4);
    }

    float S[2][16];
    for (int p = 0; p < 4; ++p) {
      __syncthreads();
      for (int i = tid; i < 2048; i += 256) {
        int m = i >> 4, jc = i & 15;
        k4[m*17 + (jc ^ ((m >> 2) & 3))] =
          *(const float4*)(qkc + ((long)(lt*NN + p*128 + m))*128 + 64 + jc*4);
      }
      __syncthreads();
      float acc00 = 0.f, acc01 = 0.f, acc02 = 0.f, acc03 = 0.f;
      float acc10 = 0.f, acc11 = 0.f, acc12 = 0.f, acc13 = 0.f;
      #pragma unroll 4
      for (int jc = 0; jc < 16; ++jc) {
        float4 q0 = q4[(qbase+0)*17 + jc];
        float4 q1 = q4[(qbase+1)*17 + jc];
        float4 kv;
        int m0 = tx;
        kv = k4[m0*17 + (jc ^ ((m0 >> 2) & 3))];
        acc00 += q0.x*kv.x + q0.y*kv.y + q0.z*kv.z + q0.w*kv.w;
        acc10 += q1.x*kv.x + q1.y*kv.y + q1.z*kv.z + q1.w*kv.w;
        int m1 = tx + 32;
        kv = k4[m1*17 + (jc ^ ((m1 >> 2) & 3))];
        acc01 += q0.x*kv.x + q0.y*kv.y + q0.z*kv.z + q0.w*kv.w;
        acc11 += q1.x*kv.x + q1.y*kv.y + q1.z*kv.z + q1.w*kv.w;
        int m2 = tx + 64;
        kv = k4[m2*17 + (jc ^ ((m2 >> 2) & 3))];
        acc02 += q0.x*kv.x + q0.y*kv.y + q0.z*kv.z + q0.w*kv.w;
        acc12 += q1.x*kv.x + q1.y*kv.y + q1.z*kv.z + q1.w*kv.w;
        int m3 = tx + 96;
        kv = k4[m3*17 + (jc ^ ((m3 >> 2) & 3))];
        acc03 += q0.x*kv.x + q0.y*kv.y + q0.z*kv.z + q0.w*kv.w;
        acc13 += q1.x*kv.x + q1.y*kv.y + q1.z*kv.z + q1.w*kv.w;
      }
      S[0][p*4+0] = acc00; S[0][p*4+1] = acc01; S[0][p*4+2] = acc02; S[0][p*4+3] = acc03;
      S[1][p*4+0] = acc10; S[1][p*4+1] = acc11; S[1][p*4+2] = acc12; S[1][p*4+3] = acc13;
    }
    __syncthreads();   // kc + qtl dead

    #pragma unroll
    for (int qi = 0; qi < 2; ++qi) {
      #pragma unroll
      for (int ig = 0; ig < 16; ++ig) S[qi][ig] *= SCALEV;
      float lm = -INFINITY;
      #pragma unroll
      for (int ig = 0; ig < 16; ++ig) {
        bool keep = ((msk[(qt*16 + qbase + qi)*16 + ig] >> tx) & 1u) != 0u;
        float v = keep ? S[qi][ig] : NEGV;
        S[qi][ig] = v;
        lm = fmaxf(lm, v);
      }
      #pragma unroll
      for (int mk = 1; mk < 32; mk <<= 1) lm = fmaxf(lm, __shfl_xor(lm, mk, 64));
      float se = 0.f;
      #pragma unroll
      for (int ig = 0; ig < 16; ++ig) {
        float ev = __expf(S[qi][ig] - lm);
        S[qi][ig] = ev;
        se += ev;
      }
      #pragma unroll
      for (int mk = 1; mk < 32; mk <<= 1) se += __shfl_xor(se, mk, 64);
      float inv = 1.f / se;
      bf16* prow = P + (qbase + qi)*520;
      #pragma unroll
      for (int ig = 0; ig < 16; ++ig)
        prow[tx + 32*ig] = f2b(S[qi][ig]*inv);
    }

    int w = tid >> 6, l = tid & 63;
    int arow = l & 15, kgrp = l >> 4;
    facc4 acc = {0.f, 0.f, 0.f, 0.f};
    for (int kh = 0; kh < 2; ++kh) {
      __syncthreads();
      for (int i = tid; i < 2048; i += 256) {
        int m2 = (i & 127) << 1;
        int cc = (i >> 7) << 2;
        const bf16* gp = vvc + ((long)(lt*NN + kh*256 + m2))*128 + 64 + cc;
        ushort4 a = *(const ushort4*)(gp);
        ushort4 b = *(const ushort4*)(gp + 128);
        *(unsigned*)(vTh + (cc+0)*264 + m2) = (unsigned)a.x | ((unsigned)b.x << 16);
        *(unsigned*)(vTh + (cc+1)*264 + m2) = (unsigned)a.y | ((unsigned)b.y << 16);
        *(unsigned*)(vTh + (cc+2)*264 + m2) = (unsigned)a.z | ((unsigned)b.z << 16);
        *(unsigned*)(vTh + (cc+3)*264 + m2) = (unsigned)a.w | ((unsigned)b.w << 16);
      }
      __syncthreads();
      const bf16* pa = P + arow*520 + kh*256 + kgrp*8;
      const bf16* pb = vTh + (w*16 + arow)*264 + kgrp*8;
      #pragma unroll
      for (int ks = 0; ks < 8; ++ks) {
        bfrag8 av = *(const bfrag8*)(pa + ks*32);
        bfrag8 bv = *(const bfrag8*)(pb + ks*32);
        acc = __builtin_amdgcn_mfma_f32_16x16x32_bf16(av, bv, acc, 0, 0, 0);
      }
    }
    // sole writer of resid2 — plain stores, race-free vs dyn's resid +=
    long rb = ((long)gt*NN + qt*16)*64 + w*16 + arow;
    #pragma unroll
    for (int r = 0; r < 4; ++r) {
      int row = kgrp*4 + r;
      resid2[rb + (long)row*64] = acc[r];
    }
    return;
  }

  // ================= dynamic attention (h = yy) =================
  float* sc    = (float*)smem;                    // [16][520] (A)
  bf16*  vT    = (bf16*)smem;                     // [32][520] (B)
  float* kt    = (float*)(smem + 33280);          // [128][36] (A)
  bf16*  p_lds = (bf16*)(smem + 33280);           // [16][520] (B)
  float* red   = (float*)(smem + 49920);          // [2][272]
  float* ulds  = (float*)(smem + 51712);          // [16][8]
  float* means = (float*)(smem + 52224);          // [16]

  int h = yy;
  int qce = h*32, kce = 64 + h*32;

  float4 q0r[8], q1r[8];
  {
    const float* qp = qkx + ((long)(lt*NN + qt*16 + qbase))*128 + qce;
    #pragma unroll
    for (int j = 0; j < 8; ++j) q0r[j] = *(const float4*)(qp + j*4);
    #pragma unroll
    for (int j = 0; j < 8; ++j) q1r[j] = *(const float4*)(qp + 128 + j*4);
  }

  float S[2][16];
  for (int p = 0; p < 4; ++p) {
    __syncthreads();
    for (int i = tid; i < 1024; i += 256) {
      int row = i >> 3, jj = (i & 7) << 2;
      *(float4*)(kt + row*36 + jj) =
        *(const float4*)(qkx + ((long)(lt*NN + p*128 + row))*128 + kce + jj);
    }
    __syncthreads();
    #pragma unroll
    for (int ii = 0; ii < 4; ++ii) {
      int m = tx + 32*ii;
      const float4* kr4 = (const float4*)(kt + m*36);
      float4 k0 = kr4[0], k1 = kr4[1], k2 = kr4[2], k3 = kr4[3];
      float4 k4 = kr4[4], k5 = kr4[5], k6 = kr4[6], k7 = kr4[7];
      // numpy einsum baseline-SIMD emulation: 4 lanes, sequential unfused
      // mul+add per lane over d = l, l+4, ..., l+28; SSE3 hadd tree at end.
      {
        float v0 = 0.f, v1 = 0.f, v2 = 0.f, v3 = 0.f;
        MULADD4(q0r[0], k0); MULADD4(q0r[1], k1); MULADD4(q0r[2], k2); MULADD4(q0r[3], k3);
        MULADD4(q0r[4], k4); MULADD4(q0r[5], k5); MULADD4(q0r[6], k6); MULADD4(q0r[7], k7);
        float s = __fadd_rn(__fadd_rn(v0, v1), __fadd_rn(v2, v3));
        s = s * 0.125f;
        S[0][p*4+ii] = s;
        sc[(qbase+0)*520 + p*128 + m] = s;
      }
      {
        float v0 = 0.f, v1 = 0.f, v2 = 0.f, v3 = 0.f;
        MULADD4(q1r[0], k0); MULADD4(q1r[1], k1); MULADD4(q1r[2], k2); MULADD4(q1r[3], k3);
        MULADD4(q1r[4], k4); MULADD4(q1r[5], k5); MULADD4(q1r[6], k6); MULADD4(q1r[7], k7);
        float s = __fadd_rn(__fadd_rn(v0, v1), __fadd_rn(v2, v3));
        s = s * 0.125f;
        S[1][p*4+ii] = s;
        sc[(qbase+1)*520 + p*128 + m] = s;
      }
    }
  }
  __syncthreads();

  // ---- T14 async-stage split: issue V-tile global loads NOW (into registers);
  //      HBM latency hides under the mean + softmax below. LDS writes deferred.
  ushort4 vpa[8], vpb[8];
  #pragma unroll
  for (int j = 0; j < 8; ++j) {
    int i = tid + j*256;
    int m2 = (i & 255) << 1;
    int cc = (i >> 8) << 2;
    const bf16* gp = vvc + ((long)(lt*NN + m2))*128 + qce + cc;
    vpa[j] = *(const ushort4*)(gp);
    vpb[j] = *(const ushort4*)(gp + 128);
  }

  // numpy pairwise mean: 4 base-blocks of 128, 8 strided accumulators each
  if (tid < 128) {
    int row = tid >> 3, b = (tid >> 1) & 3, hh = tid & 1;
    const float* a = sc + row*520 + b*128 + hh*4;
    float4 r4 = *(const float4*)a;
    #pragma unroll
    for (int i = 8; i < 128; i += 8) {
      float4 v = *(const float4*)(a + i);
      r4.x = __fadd_rn(r4.x, v.x); r4.y = __fadd_rn(r4.y, v.y);
      r4.z = __fadd_rn(r4.z, v.z); r4.w = __fadd_rn(r4.w, v.w);
    }
    ulds[row*8 + b*2 + hh] = __fadd_rn(__fadd_rn(r4.x, r4.y), __fadd_rn(r4.z, r4.w));
  }
  __syncthreads();
  if (tid < 16) {
    const float* ur = ulds + tid*8;
    float p0 = __fadd_rn(ur[0], ur[1]);
    float p1 = __fadd_rn(ur[2], ur[3]);
    float p2 = __fadd_rn(ur[4], ur[5]);
    float p3 = __fadd_rn(ur[6], ur[7]);
    means[tid] = __fadd_rn(__fadd_rn(p0, p1), __fadd_rn(p2, p3)) * (1.f/512.f);
  }
  __syncthreads();   // all sc reads complete — vT (aliasing sc) may be written after this

  long obase = ((long)(gt*2 + h))*NN*NN;
  #pragma unroll
  for (int qi = 0; qi < 2; ++qi) {
    float mn = means[qbase + qi];
    unsigned kmask = 0; float lm = -INFINITY;
    #pragma unroll
    for (int ig = 0; ig < 16; ++ig) {
      if (S[qi][ig] >= mn) { kmask |= (1u << ig); lm = fmaxf(lm, S[qi][ig]); }
    }
    #pragma unroll
    for (int mk = 1; mk < 32; mk <<= 1) lm = fmaxf(lm, __shfl_xor(lm, mk, 64));
    float e[16]; float se = 0.f;
    #pragma unroll
    for (int ig = 0; ig < 16; ++ig) {
      e[ig] = ((kmask >> ig) & 1u) ? __expf(S[qi][ig] - lm) : 0.f;
      se += e[ig];
    }
    #pragma unroll
    for (int mk = 1; mk < 32; mk <<= 1) se += __shfl_xor(se, mk, 64);
    float inv = 1.f/se;
    float* rowp = attn_out + obase + (long)(qt*16 + qbase + qi)*NN;
    bf16* prow = p_lds + (qbase + qi)*520;
    #pragma unroll
    for (int ig = 0; ig < 16; ++ig) {
      float pr = e[ig]*inv;
      __builtin_nontemporal_store(pr, rowp + tx + 32*ig);   // write-once output
      prow[tx + 32*ig] = f2b(pr);
    }
  }

  // write prefetched V^T registers to LDS (same pack arithmetic as round 6)
  #pragma unroll
  for (int j = 0; j < 8; ++j) {
    int i = tid + j*256;
    int m2 = (i & 255) << 1;
    int cc = (i >> 8) << 2;
    *(unsigned*)(vT + (cc+0)*520 + m2) = (unsigned)vpa[j].x | ((unsigned)vpb[j].x << 16);
    *(unsigned*)(vT + (cc+1)*520 + m2) = (unsigned)vpa[j].y | ((unsigned)vpb[j].y << 16);
    *(unsigned*)(vT + (cc+2)*520 + m2) = (unsigned)vpa[j].z | ((unsigned)vpb[j].z << 16);
    *(unsigned*)(vT + (cc+3)*520 + m2) = (unsigned)vpa[j].w | ((unsigned)vpb[j].w << 16);
  }
  __syncthreads();

  {
    int w = tid >> 6, l = tid & 63;
    int nh = w & 1, kh = w >> 1;
    int arow = l & 15, kgrp = l >> 4;
    facc4 acc = {0.f, 0.f, 0.f, 0.f};
    const bf16* pa = p_lds + arow*520 + kh*256 + kgrp*8;
    const bf16* pb = vT + (nh*16 + arow)*520 + kh*256 + kgrp*8;
    #pragma unroll
    for (int ks = 0; ks < 8; ++ks) {
      bfrag8 av = *(const bfrag8*)(pa + ks*32);
      bfrag8 bv = *(const bfrag8*)(pb + ks*32);
      acc = __builtin_amdgcn_mfma_f32_16x16x32_bf16(av, bv, acc, 0, 0, 0);
    }
    if (w >= 2) {
      #pragma unroll
      for (int r = 0; r < 4; ++r)
        red[nh*272 + (kgrp*4 + r)*17 + arow] = acc[r];
    }
    __syncthreads();
    if (w < 2) {
      // dyn heads write disjoint column ranges (h*32..h*32+31) — race-free
      long rb = ((long)gt*NN + qt*16)*64 + h*32 + nh*16 + arow;
      #pragma unroll
      for (int r = 0; r < 4; ++r) {
        int row = kgrp*4 + r;
        resid[rb + (long)row*64] += acc[r] + red[nh*272 + row*17 + arow];
      }
    }
  }
}

// ---------------- LN1 fused into MLP gemm1 (reads resid + resid2) ----------------
__global__ __launch_bounds__(256) void k_mlp1(
  const float* __restrict__ resid, const float* __restrict__ resid2,
  const float* __restrict__ g1, const float* __restrict__ b1,
  const float* __restrict__ B, const float* __restrict__ bias, float* __restrict__ C)
{
  __shared__ float As[64][68];
  __shared__ float Bs[64][68];
  int rt = blockIdx.x, bcn = blockIdx.y;
  int tid = threadIdx.x;
  int tx = tid & 15, ty = tid >> 4;
  int wave = tid >> 6, lane = tid & 63;
  for (int rr = wave; rr < 64; rr += 4) {
    long idx = ((long)rt*64 + rr)*64 + lane;
    float v = resid[idx] + resid2[idx];   // (h+dyn)+st — round-4 association
    float m = wsum64(v)*(1.f/64.f);
    float d = v - m;
    float var = wsum64(d*d)*(1.f/64.f);
    As[lane][rr] = d*rsqrtf(var + 1e-5f)*g1[lane] + b1[lane];
  }
  #pragma unroll
  for (int i = 0; i < 4; ++i) {
    int t = i*256 + tid;
    int m = t >> 4, kq = (t & 15)*4;
    float4 bv = *(const float4*)&B[(long)(bcn*64 + m)*64 + kq];
    Bs[kq+0][m] = bv.x; Bs[kq+1][m] = bv.y; Bs[kq+2][m] = bv.z; Bs[kq+3][m] = bv.w;
  }
  __syncthreads();
  float acc[4][4] = {{0.f}};
  #pragma unroll 8
  for (int kk = 0; kk < 64; ++kk) {
    float4 a4 = *(const float4*)&As[kk][ty*4];
    float4 b4 = *(const float4*)&Bs[kk][tx*4];
    acc[0][0] += a4.x*b4.x; acc[0][1] += a4.x*b4.y; acc[0][2] += a4.x*b4.z; acc[0][3] += a4.x*b4.w;
    acc[1][0] += a4.y*b4.x; acc[1][1] += a4.y*b4.y; acc[1][2] += a4.y*b4.z; acc[1][3] += a4.y*b4.w;
    acc[2][0] += a4.z*b4.x; acc[2][1] += a4.z*b4.y; acc[2][2] += a4.z*b4.z; acc[2][3] += a4.z*b4.w;
    acc[3][0] += a4.w*b4.x; acc[3][1] += a4.w*b4.y; acc[3][2] += a4.w*b4.z; acc[3][3] += a4.w*b4.w;
  }
  #pragma unroll
  for (int i = 0; i < 4; ++i) {
    long ro = (long)(rt*64 + ty*4 + i)*128 + bcn*64 + tx*4;
    #pragma unroll
    for (int j = 0; j < 4; ++j) C[ro + j] = acc[i][j] + bias[bcn*64 + tx*4 + j];
  }
}

// ---------------- LN2 + leaky + PE fused into mha in-projection (resid + resid2) ----
__global__ __launch_bounds__(256) void k_mha_in(
  const float* __restrict__ mlpo, const float* __restrict__ resid,
  const float* __restrict__ resid2,
  const float* __restrict__ g2, const float* __restrict__ b2,
  const float* __restrict__ B, const float* __restrict__ bias, bf16* __restrict__ C)
{
  __shared__ float As[64][68];
  __shared__ float Bs[64][68];
  int rt = blockIdx.x, bcn = blockIdx.y;
  int tid = threadIdx.x;
  int tx = tid & 15, ty = tid >> 4;
  int wave = tid >> 6, lane = tid & 63;
  for (int rr = wave; rr < 64; rr += 4) {
    long r = (long)rt*64 + rr;
    float rf = resid[r*64 + lane] + resid2[r*64 + lane];  // == round-4 resid
    float v = mlpo[r*64 + lane] + rf;
    float m = wsum64(v)*(1.f/64.f);
    float d = v - m;
    float var = wsum64(d*d)*(1.f/64.f);
    float y = d*rsqrtf(var + 1e-5f)*g2[lane] + b2[lane];
    y = lk(y);
    float tf = (float)(r / NN);
    float dv = __expf(-(float)(lane & ~1) * 0.14391156831212787f);
    float pe = (lane & 1) ? cosf(tf*dv) : sinf(tf*dv);
    As[lane][rr] = y + pe;
  }
  #pragma unroll
  for (int i = 0; i < 4; ++i) {
    int t = i*256 + tid;
    int m = t >> 4, kq = (t & 15)*4;
    float4 bv = *(const float4*)&B[(long)(bcn*64 + m)*64 + kq];
    Bs[kq+0][m] = bv.x; Bs[kq+1][m] = bv.y; Bs[kq+2][m] = bv.z; Bs[kq+3][m] = bv.w;
  }
  __syncthreads();
  float acc[4][4] = {{0.f}};
  #pragma unroll 8
  for (int kk = 0; kk < 64; ++kk) {
    float4 a4 = *(const float4*)&As[kk][ty*4];
    float4 b4 = *(const float4*)&Bs[kk][tx*4];
    acc[0][0] += a4.x*b4.x; acc[0][1] += a4.x*b4.y; acc[0][2] += a4.x*b4.z; acc[0][3] += a4.x*b4.w;
    acc[1][0] += a4.y*b4.x; acc[1][1] += a4.y*b4.y; acc[1][2] += a4.y*b4.z; acc[1][3] += a4.y*b4.w;
    acc[2][0] += a4.z*b4.x; acc[2][1] += a4.z*b4.y; acc[2][2] += a4.z*b4.z; acc[2][3] += a4.z*b4.w;
    acc[3][0] += a4.w*b4.x; acc[3][1] += a4.w*b4.y; acc[3][2] += a4.w*b4.z; acc[3][3] += a4.w*b4.w;
  }
  #pragma unroll
  for (int i = 0; i < 4; ++i) {
    long ro = (long)(rt*64 + ty*4 + i)*192 + bcn*64 + tx*4;
    #pragma unroll
    for (int j = 0; j < 4; ++j) C[ro + j] = f2b(acc[i][j] + bias[bcn*64 + tx*4 + j]);
  }
}

// ---------------- head ----------------
__global__ __launch_bounds__(64) void k_head(
  const bf16* __restrict__ mqkv, const float* __restrict__ rts,
  const float* __restrict__ mow, const float* __restrict__ mob,
  const float* __restrict__ xsw, const float* __restrict__ xtw, const float* __restrict__ xtb,
  const float* __restrict__ hw, const float* __restrict__ hb,
  const float* __restrict__ linw, const float* __restrict__ linb,
  float* __restrict__ out)
{
  int n = blockIdx.x, o = threadIdx.x;
  __shared__ float ps[TT];
  __shared__ float buf[64], buf2[64];
  float mq = b2f(mqkv[((long)(TT-1)*NN + n)*192 + o]);
  for (int s = 0; s < TT; ++s) {
    float v = mq * b2f(mqkv[((long)s*NN + n)*192 + 64 + o]);
    v = wsum64(v);
    if (o == 0) ps[s] = v * SCALEV;
  }
  __syncthreads();
  float x = (o < TT) ? ps[o] : -INFINITY;
  float mx = wmax64(x);
  float e = (o < TT) ? __expf(x - mx) : 0.f;
  float se = wsum64(e);
  if (o < TT) ps[o] = e / se;
  __syncthreads();
  float acc = 0.f;
  for (int s = 0; s < TT; ++s) acc += ps[s]*b2f(mqkv[((long)s*NN + n)*192 + 128 + o]);
  buf[o] = acc;
  __syncthreads();
  float acc2 = mob[o];
  for (int k = 0; k < 64; ++k) acc2 += buf[k]*mow[o*64 + k];
  float m2 = wsum64(acc2)*(1.f/64.f);
  float d2 = acc2 - m2;
  float var2 = wsum64(d2*d2)*(1.f/64.f);
  float a = d2*rsqrtf(var2 + 1e-5f);
  float rt = rts[(long)n*64 + o];
  __syncthreads();
  buf[o] = a; buf2[o] = rt;
  __syncthreads();
  float pre = xtb[o];
  for (int k = 0; k < 64; ++k) pre += buf[k]*xsw[o*64 + k] + buf2[k]*xtw[o*64 + k];
  float zg = sgm(pre);
  float u = zg*a + (1.f - zg)*rt;
  __syncthreads();
  buf[o] = u;
  __syncthreads();
  float f = hb[o];
  for (int k = 0; k < 64; ++k) f += buf[k]*hw[o*64 + k];
  f = lk(f);
  float tot = wsum64(f * linw[o]);
  if (o == 0) out[n] = tot + linb[0];
}

// =======================================================================
extern "C" void kernel_launch(void* const* d_in, const int* in_sizes, int n_in,
                              void* d_out, int out_size, void* d_ws, size_t ws_size,
                              hipStream_t stream)
{
  const float* x    = (const float*)d_in[0];
  const int*   ei   = (const int*)  d_in[1];
  const float* fcw  = (const float*)d_in[2];
  const float* fcb  = (const float*)d_in[3];
  const float* wih0 = (const float*)d_in[4];
  const float* whh0 = (const float*)d_in[5];
  const float* bih0 = (const float*)d_in[6];
  const float* bhh0 = (const float*)d_in[7];
  const float* wih1 = (const float*)d_in[8];
  const float* whh1 = (const float*)d_in[9];
  const float* bih1 = (const float*)d_in[10];
  const float* bhh1 = (const float*)d_in[11];
  const float* dmqw = (const float*)d_in[12];
  const float* dmkw = (const float*)d_in[13];
  const float* dmvw = (const float*)d_in[14];
  const float* dmvb = (const float*)d_in[15];
  const float* ssqw = (const float*)d_in[16];
  const float* sskw = (const float*)d_in[17];
  const float* ssvw = (const float*)d_in[18];
  const float* ssvb = (const float*)d_in[19];
  const float* ln1g = (const float*)d_in[20];
  const float* ln1b = (const float*)d_in[21];
  const float* ln2g = (const float*)d_in[22];
  const float* ln2b = (const float*)d_in[23];
  const float* mw1  = (const float*)d_in[24];
  const float* mb1  = (const float*)d_in[25];
  const float* mw2  = (const float*)d_in[26];
  const float* mb2  = (const float*)d_in[27];
  const float* mhw  = (const float*)d_in[28];
  const float* mhb  = (const float*)d_in[29];
  const float* mow  = (const float*)d_in[30];
  const float* mob  = (const float*)d_in[31];
  const float* gxsw = (const float*)d_in[32];
  const float* gxtw = (const float*)d_in[33];
  const float* gxtb = (const float*)d_in[34];
  const float* ghw  = (const float*)d_in[35];
  const float* ghb  = (const float*)d_in[36];
  const float* linw = (const float*)d_in[37];
  const float* linb = (const float*)d_in[38];

  // ---- workspace layout (~43.6 MB envelope) ----
  char* base = (char*)d_ws;
  float*  xs    = (float*)(base);                 // xs f32; later mlpo f32
  char*   Rb    = base + 7864320;                 // shared region (15.73 MB):
  float*  qkc   = (float*)Rb;                     //   per-chunk qs|ks f32 (5.24MB)
  bf16*   vvc   = (bf16*)(Rb + 5242880);          //   per-chunk v|vs bf16 (2.62MB)
  float*  qkx   = (float*)(Rb + 7864320);         //   per-chunk exact q|k f32 (5.24MB)
  float*  mlph  = (float*)Rb;                     //   later: mlp hidden f32
  bf16*   mqkv  = (bf16*)Rb;                      //   later: mha qkv bf16
  bf16*   g0    = (bf16*)(base + 23592960);
  float*  resid = (float*)(base + 27525120);      // h + dyn
  float*  resid2= (float*)(base + 35389440);      // static-attn contribution (7.86MB)
  float*  rts   = (float*)(base + 43253760);
  unsigned int* msk = (unsigned int*)(base + 43384832);
  float*  Wall  = (float*)(base + 43417600);      // 6*4096 f32 (q|k|qs|ks|v|vs)
  float*  bcV   = (float*)(base + 43515904);      // 128 f32
  float*  mlpo  = xs;
  float*  outb  = (float*)d_out;
  float*  attn  = outb + 512;
  // gi staged in d_out's attn region — dead before k_attn writes probs
  float*  gi    = (float*)((char*)d_out + 2048);

  k_pack<<<dim3(98), 256, 0, stream>>>(dmqw, dmkw, ssqw, sskw, dmvw, ssvw, dmvb, ssvb, ei, msk, Wall, bcV);
  k_fcin<<<dim3(TN*64/256), 256, 0, stream>>>(x, fcw, fcb, xs, resid);
  // GRU layer 0
  k_gemm<float,float><<<dim3(480, 3), 256, 0, stream>>>(xs, wih0, bih0, gi, 64, 192, 1);
  k_gru<<<dim3(NN), 192, 0, stream>>>(gi, whh0, bhh0, g0, nullptr, 0);
  // GRU layer 1
  k_gemm<bf16,float><<<dim3(480, 3), 256, 0, stream>>>(g0, wih1, bih1, gi, 64, 192, 1);
  k_gru<<<dim3(NN), 192, 0, stream>>>(gi, whh1, bhh1, nullptr, rts, 1);
  // attention in 3 t-chunks of 20 (dyn + static merged, XCD-swizzled 1D grid)
  for (int tc = 0; tc < NCHK; ++tc) {
    const float* xsc = xs + (size_t)tc*TCH*NN*64;
    k_proj<<<dim3(TCH*NN/64, 6), 256, 0, stream>>>(xsc, Wall, bcV, qkx, qkc, vvc);
    k_attn<<<dim3(1920), 256, 0, stream>>>(qkx, qkc, vvc, msk, attn, resid, resid2, tc);
  }
  // LN1+MLP1 -> MLP2 -> LN2+PE+mha-in -> head
  k_mlp1<<<dim3(480, 2), 256, 0, stream>>>(resid, resid2, ln1g, ln1b, mw1, mb1, mlph);
  k_gemm<float,float><<<dim3(480, 1), 256, 0, stream>>>(mlph, mw2, mb2, mlpo, 128, 64, 0);
  k_mha_in<<<dim3(480, 3), 256, 0, stream>>>(mlpo, resid, resid2, ln2g, ln2b, mhw, mhb, mqkv);
  k_head<<<dim3(NN), 64, 0, stream>>>(mqkv, rts, mow, mob, gxsw, gxtw, gxtb, ghw, ghb, linw, linb, outb);
}

// Round 11
// 691.487 us; speedup vs baseline: 1.1207x; 1.0320x over previous
//
#include <hip/hip_runtime.h>
#include <hip/hip_bf16.h>

#define NN 512
#define TT 60
#define DFF 6
#define EE 8192
#define TN (TT*NN)
#define TCH 20          // t-chunk size
#define NCHK 3          // number of t-chunks
#define SCALEV 0.125f
#define NEGV -1.0e10f

typedef __hip_bfloat16 bf16;
using bfrag8 = __attribute__((ext_vector_type(8))) short;   // 8 bf16 (4 VGPRs)
using facc4  = __attribute__((ext_vector_type(4))) float;   // 4 f32 acc

__device__ __forceinline__ float b2f(bf16 v){ return __bfloat162float(v); }
__device__ __forceinline__ bf16 f2b(float v){ return __float2bfloat16(v); }
__device__ __forceinline__ float lk(float x){ return x >= 0.f ? x : 0.01f*x; }
__device__ __forceinline__ float sgm(float x){ return 1.f/(1.f+__expf(-x)); }

__device__ __forceinline__ float ldf(const float* p, long i){ return p[i]; }
__device__ __forceinline__ float ldf(const bf16* p, long i){ return b2f(p[i]); }
__device__ __forceinline__ void stf(float* p, long i, float v){ p[i] = v; }
__device__ __forceinline__ void stf(bf16* p, long i, float v){ p[i] = f2b(v); }

__device__ __forceinline__ float4 ld4f(const float* p){ return *(const float4*)p; }
__device__ __forceinline__ float4 ld4f(const bf16* p){
  ushort4 u = *(const ushort4*)p;
  float4 f;
  f.x = b2f(*(const bf16*)&u.x);
  f.y = b2f(*(const bf16*)&u.y);
  f.z = b2f(*(const bf16*)&u.z);
  f.w = b2f(*(const bf16*)&u.w);
  return f;
}

__device__ __forceinline__ float wsum64(float v){
  #pragma unroll
  for (int off = 32; off; off >>= 1) v += __shfl_xor(v, off, 64);
  return v;
}
__device__ __forceinline__ float wmax64(float v){
  #pragma unroll
  for (int off = 32; off; off >>= 1) v = fmaxf(v, __shfl_xor(v, off, 64));
  return v;
}

// ---------------- pack (blocks 0..96) + adjacency bitmask (block 97, LDS atomics) ----
__global__ __launch_bounds__(256) void k_pack(
  const float* __restrict__ qw, const float* __restrict__ kw,
  const float* __restrict__ qsw, const float* __restrict__ ksw,
  const float* __restrict__ vw, const float* __restrict__ vsw,
  const float* __restrict__ vb, const float* __restrict__ vsb,
  const int* __restrict__ ei, unsigned int* __restrict__ msk,
  float* __restrict__ Wall, float* __restrict__ bcV)
{
  __shared__ unsigned int lmsk[8192];
  int tid = threadIdx.x;
  if (blockIdx.x == 97) {
    for (int i = tid; i < 8192; i += 256) lmsk[i] = 0u;
    __syncthreads();
    for (int e = tid; e < EE; e += 256) {
      int u = ei[e], v = ei[EE + e];
      atomicOr(&lmsk[u*16 + (v >> 5)], 1u << (v & 31));
    }
    __syncthreads();
    for (int i = tid; i < 8192; i += 256) msk[i] = lmsk[i];
    return;
  }
  int idx = blockIdx.x*256 + tid;
  if (idx < 6*4096) {
    int which = idx >> 12, rem = idx & 4095;
    const float* s = (which==0)?qw:(which==1)?kw:(which==2)?qsw:(which==3)?ksw:(which==4)?vw:vsw;
    Wall[idx] = s[rem];
  } else if (idx < 6*4096 + 128) {
    int o = idx - 6*4096;
    bcV[o] = (o < 64) ? vb[o] : vsb[o-64];
  }
}

// ---------------- fc_in: np-exact fp32 (seq-FMA over k, bias added after) ----------------
__global__ __launch_bounds__(256) void k_fcin(
  const float* __restrict__ x, const float* __restrict__ w, const float* __restrict__ b,
  float* __restrict__ xs, float* __restrict__ resid)
{
  long idx = (long)blockIdx.x*256 + threadIdx.x;   // < TN*64
  int o = idx & 63;
  long r = idx >> 6;                // r = t*NN + n
  int t = (int)(r / NN), n = (int)(r % NN);
  const float* xr = x + ((long)n*TT + t)*DFF;
  const float* wr = w + o*DFF;
  float acc = 0.f;
  #pragma unroll
  for (int j = 0; j < DFF; ++j) acc = fmaf(xr[j], wr[j], acc);
  float h = __fadd_rn(acc, b[o]);
  xs[idx] = h;
  resid[idx] = h;
}

// ---------------- fused per-chunk projection (np-exact seq-FMA over k=0..63) ----------------
__global__ __launch_bounds__(256) void k_proj(
  const float* __restrict__ A, const float* __restrict__ Wall, const float* __restrict__ bcV,
  float* __restrict__ qkx, float* __restrict__ qkc, bf16* __restrict__ vvc)
{
  __shared__ float As[64][68];
  __shared__ float Bs[64][68];
  int rt = blockIdx.x, bcn = blockIdx.y;
  const float* B = Wall + bcn*4096;
  int tid = threadIdx.x;
  int tx = tid & 15, ty = tid >> 4;
  float acc[4][4] = {{0.f}};
  #pragma unroll
  for (int i = 0; i < 4; ++i) {
    int t = i*256 + tid;
    int m = t >> 4, kq = (t & 15)*4;
    float4 av = *(const float4*)&A[(long)(rt*64 + m)*64 + kq];
    As[kq+0][m] = av.x; As[kq+1][m] = av.y; As[kq+2][m] = av.z; As[kq+3][m] = av.w;
    float4 bv = *(const float4*)&B[(long)m*64 + kq];
    Bs[kq+0][m] = bv.x; Bs[kq+1][m] = bv.y; Bs[kq+2][m] = bv.z; Bs[kq+3][m] = bv.w;
  }
  __syncthreads();
  for (int kk = 0; kk < 64; ++kk) {
    float4 a4 = *(const float4*)&As[kk][ty*4];
    float4 b4 = *(const float4*)&Bs[kk][tx*4];
    acc[0][0] = fmaf(a4.x,b4.x,acc[0][0]); acc[0][1] = fmaf(a4.x,b4.y,acc[0][1]); acc[0][2] = fmaf(a4.x,b4.z,acc[0][2]); acc[0][3] = fmaf(a4.x,b4.w,acc[0][3]);
    acc[1][0] = fmaf(a4.y,b4.x,acc[1][0]); acc[1][1] = fmaf(a4.y,b4.y,acc[1][1]); acc[1][2] = fmaf(a4.y,b4.z,acc[1][2]); acc[1][3] = fmaf(a4.y,b4.w,acc[1][3]);
    acc[2][0] = fmaf(a4.z,b4.x,acc[2][0]); acc[2][1] = fmaf(a4.z,b4.y,acc[2][1]); acc[2][2] = fmaf(a4.z,b4.z,acc[2][2]); acc[2][3] = fmaf(a4.z,b4.w,acc[2][3]);
    acc[3][0] = fmaf(a4.w,b4.x,acc[3][0]); acc[3][1] = fmaf(a4.w,b4.y,acc[3][1]); acc[3][2] = fmaf(a4.w,b4.z,acc[3][2]); acc[3][3] = fmaf(a4.w,b4.w,acc[3][3]);
  }
  if (bcn < 4) {
    float* C = (bcn < 2) ? qkx : qkc;
    int cb = (bcn & 1)*64;
    #pragma unroll
    for (int i = 0; i < 4; ++i) {
      long ro = (long)(rt*64 + ty*4 + i)*128 + cb + tx*4;
      #pragma unroll
      for (int j = 0; j < 4; ++j) C[ro + j] = acc[i][j];
    }
  } else {
    int cb = (bcn - 4)*64;
    float bv[4];
    #pragma unroll
    for (int j = 0; j < 4; ++j) bv[j] = bcV[cb + tx*4 + j];
    #pragma unroll
    for (int i = 0; i < 4; ++i) {
      long ro = (long)(rt*64 + ty*4 + i)*128 + cb + tx*4;
      #pragma unroll
      for (int j = 0; j < 4; ++j) vvc[ro + j] = f2b(acc[i][j] + bv[j]);
    }
  }
}

// ---------------- generic projection GEMM (fp32, tolerant paths) ----------------
template<typename TA, typename TC>
__global__ __launch_bounds__(256) void k_gemm(
  const TA* __restrict__ A, const float* __restrict__ B, const float* __restrict__ bias,
  TC* __restrict__ C, int KD, int NC, int gather)
{
  __shared__ float As[64][68];
  __shared__ float Bs[64][68];
  int rt = blockIdx.x, bcn = blockIdx.y;
  int tid = threadIdx.x;
  int tx = tid & 15, ty = tid >> 4;
  float acc[4][4] = {{0.f}};
  int nch = KD >> 6;
  for (int kc = 0; kc < nch; ++kc) {
    __syncthreads();
    #pragma unroll
    for (int i = 0; i < 4; ++i) {
      int t = i*256 + tid;
      int m = t >> 4, kq = (t & 15)*4;
      long aoff;
      int r = rt*64 + m;
      if (gather) { int n2 = r / TT, t2 = r - n2*TT; aoff = ((long)t2*NN + n2)*64 + kc*64 + kq; }
      else aoff = (long)r*KD + kc*64 + kq;
      float4 av = ld4f(A + aoff);
      As[kq+0][m] = av.x; As[kq+1][m] = av.y; As[kq+2][m] = av.z; As[kq+3][m] = av.w;
      int col = bcn*64 + m;
      float4 bv = *(const float4*)&B[(long)col*KD + kc*64 + kq];
      Bs[kq+0][m] = bv.x; Bs[kq+1][m] = bv.y; Bs[kq+2][m] = bv.z; Bs[kq+3][m] = bv.w;
    }
    __syncthreads();
    #pragma unroll 8
    for (int kk = 0; kk < 64; ++kk) {
      float4 a4 = *(const float4*)&As[kk][ty*4];
      float4 b4 = *(const float4*)&Bs[kk][tx*4];
      acc[0][0] += a4.x*b4.x; acc[0][1] += a4.x*b4.y; acc[0][2] += a4.x*b4.z; acc[0][3] += a4.x*b4.w;
      acc[1][0] += a4.y*b4.x; acc[1][1] += a4.y*b4.y; acc[1][2] += a4.y*b4.z; acc[1][3] += a4.y*b4.w;
      acc[2][0] += a4.z*b4.x; acc[2][1] += a4.z*b4.y; acc[2][2] += a4.z*b4.z; acc[2][3] += a4.z*b4.w;
      acc[3][0] += a4.w*b4.x; acc[3][1] += a4.w*b4.y; acc[3][2] += a4.w*b4.z; acc[3][3] += a4.w*b4.w;
    }
  }
  float bv[4];
  #pragma unroll
  for (int j = 0; j < 4; ++j) bv[j] = bias ? bias[bcn*64 + tx*4 + j] : 0.f;
  #pragma unroll
  for (int i = 0; i < 4; ++i) {
    long ro = (long)(rt*64 + ty*4 + i)*NC + bcn*64 + tx*4;
    #pragma unroll
    for (int j = 0; j < 4; ++j) stf(C, ro + j, acc[i][j] + bv[j]);
  }
}

// ---------------- GRU recurrence: one block (192 thr) per batch row ----------------
__global__ __launch_bounds__(192) void k_gru(
  const float* __restrict__ gi, const float* __restrict__ whh, const float* __restrict__ bhh,
  bf16* __restrict__ g_out, float* __restrict__ res_out, int layer)
{
  int n = blockIdx.x;
  int tid = threadIdx.x;
  int g = tid >> 6, o = tid & 63;
  __shared__ __align__(16) float h_lds[64];
  __shared__ float ghs[3][64];
  float4 w4[16];
  #pragma unroll
  for (int k4 = 0; k4 < 16; ++k4)
    w4[k4] = *(const float4*)&whh[(long)(g*64+o)*64 + k4*4];
  float bh = bhh[g*64+o];
  float ir = 0.f, iz = 0.f, inn = 0.f;
  if (tid < 64) {
    h_lds[tid] = 0.f;
    const float* gp = gi + ((long)n*TT + 0)*192;
    ir = gp[o]; iz = gp[64+o]; inn = gp[128+o];
  }
  __syncthreads();
  const float4* h4 = (const float4*)h_lds;
  for (int t = 0; t < TT; ++t) {
    float p0 = 0.f, p1 = 0.f, p2 = 0.f, p3 = 0.f;
    #pragma unroll
    for (int k4 = 0; k4 < 16; ++k4) {
      float4 hv = h4[k4];
      p0 = fmaf(w4[k4].x, hv.x, p0);
      p1 = fmaf(w4[k4].y, hv.y, p1);
      p2 = fmaf(w4[k4].z, hv.z, p2);
      p3 = fmaf(w4[k4].w, hv.w, p3);
    }
    ghs[g][o] = bh + ((p0 + p1) + (p2 + p3));
    __syncthreads();
    if (tid < 64) {
      float r = sgm(ir + ghs[0][o]);
      float z = sgm(iz + ghs[1][o]);
      float nn2 = tanhf(inn + r*ghs[2][o]);
      float hn = (1.f - z)*nn2 + z*h_lds[o];
      h_lds[o] = hn;
      if (layer == 0) g_out[((long)t*NN + n)*64 + o] = f2b(hn);
      else if (t == TT-1) res_out[(long)n*64 + o] = lk(hn);
      if (t + 1 < TT) {
        const float* gp = gi + ((long)n*TT + t + 1)*192;
        ir = gp[o]; iz = gp[64+o]; inn = gp[128+o];
      }
    }
    __syncthreads();
  }
}

// ---------------- merged attention, XCD-swizzled 1D grid (1920 blocks) ----------------
// Round-8 known-good structure (52288 B LDS, 3 blocks/CU, LDS mean, V-prefetch).
// NOTE (round-9 lesson): do NOT add phase-A register double-buffering here — the
// prefetched tiles' live range crosses the register-pressure peak and LLVM spills
// to scratch WITHOUT raising VGPR_Count (FETCH/WRITE_SIZE balloon instead).
#define MULADD4(QV, KV) \
  v0 = __fadd_rn(v0, __fmul_rn((QV).x, (KV).x)); \
  v1 = __fadd_rn(v1, __fmul_rn((QV).y, (KV).y)); \
  v2 = __fadd_rn(v2, __fmul_rn((QV).z, (KV).z)); \
  v3 = __fadd_rn(v3, __fmul_rn((QV).w, (KV).w));

__global__ __launch_bounds__(256, 3) void k_attn(
  const float* __restrict__ qkx, const float* __restrict__ qkc,
  const bf16* __restrict__ vvc, const unsigned int* __restrict__ msk,
  float* __restrict__ attn_out, float* __restrict__ resid,
  float* __restrict__ resid2, int tc)
{
  __shared__ __align__(16) char smem[52288];
  int bid = blockIdx.x;
  int vid = (bid & 7)*240 + (bid >> 3);
  int lt = vid / 96;
  int rem = vid - lt*96;
  int yy = rem >> 5;
  int qt = rem & 31;
  int gt = tc*TCH + lt;
  int tid = threadIdx.x, tx = tid & 31, grp = tid >> 5;
  int qbase = grp*2;

  if (yy == 2) {
    // ================= static attention =================
    float* kc  = (float*)smem;                 // [128][68] f32 swizzled (A)
    bf16*  vTh = (bf16*)smem;                  // [64][264] bf16 (B)
    float* qtl = (float*)(smem + 34816);       // [16][68] f32 (A)
    bf16*  P   = (bf16*)(smem + 34816);        // [16][520] bf16 (B)

    float4* q4 = (float4*)qtl;    // stride 17 float4
    float4* k4 = (float4*)kc;     // stride 17 float4

    {
      int m = tid >> 4, jc = tid & 15;
      q4[m*17 + jc] = *(const float4*)(qkc + ((long)(lt*NN + qt*16 + m))*128 + jc*4);
    }

    float S[2][16];
    for (int p = 0; p < 4; ++p) {
      __syncthreads();
      for (int i = tid; i < 2048; i += 256) {
        int m = i >> 4, jc = i & 15;
        k4[m*17 + (jc ^ ((m >> 2) & 3))] =
          *(const float4*)(qkc + ((long)(lt*NN + p*128 + m))*128 + 64 + jc*4);
      }
      __syncthreads();
      float acc00 = 0.f, acc01 = 0.f, acc02 = 0.f, acc03 = 0.f;
      float acc10 = 0.f, acc11 = 0.f, acc12 = 0.f, acc13 = 0.f;
      #pragma unroll 4
      for (int jc = 0; jc < 16; ++jc) {
        float4 q0 = q4[(qbase+0)*17 + jc];
        float4 q1 = q4[(qbase+1)*17 + jc];
        float4 kv;
        int m0 = tx;
        kv = k4[m0*17 + (jc ^ ((m0 >> 2) & 3))];
        acc00 += q0.x*kv.x + q0.y*kv.y + q0.z*kv.z + q0.w*kv.w;
        acc10 += q1.x*kv.x + q1.y*kv.y + q1.z*kv.z + q1.w*kv.w;
        int m1 = tx + 32;
        kv = k4[m1*17 + (jc ^ ((m1 >> 2) & 3))];
        acc01 += q0.x*kv.x + q0.y*kv.y + q0.z*kv.z + q0.w*kv.w;
        acc11 += q1.x*kv.x + q1.y*kv.y + q1.z*kv.z + q1.w*kv.w;
        int m2 = tx + 64;
        kv = k4[m2*17 + (jc ^ ((m2 >> 2) & 3))];
        acc02 += q0.x*kv.x + q0.y*kv.y + q0.z*kv.z + q0.w*kv.w;
        acc12 += q1.x*kv.x + q1.y*kv.y + q1.z*kv.z + q1.w*kv.w;
        int m3 = tx + 96;
        kv = k4[m3*17 + (jc ^ ((m3 >> 2) & 3))];
        acc03 += q0.x*kv.x + q0.y*kv.y + q0.z*kv.z + q0.w*kv.w;
        acc13 += q1.x*kv.x + q1.y*kv.y + q1.z*kv.z + q1.w*kv.w;
      }
      S[0][p*4+0] = acc00; S[0][p*4+1] = acc01; S[0][p*4+2] = acc02; S[0][p*4+3] = acc03;
      S[1][p*4+0] = acc10; S[1][p*4+1] = acc11; S[1][p*4+2] = acc12; S[1][p*4+3] = acc13;
    }
    __syncthreads();   // kc + qtl dead

    #pragma unroll
    for (int qi = 0; qi < 2; ++qi) {
      #pragma unroll
      for (int ig = 0; ig < 16; ++ig) S[qi][ig] *= SCALEV;
      float lm = -INFINITY;
      #pragma unroll
      for (int ig = 0; ig < 16; ++ig) {
        bool keep = ((msk[(qt*16 + qbase + qi)*16 + ig] >> tx) & 1u) != 0u;
        float v = keep ? S[qi][ig] : NEGV;
        S[qi][ig] = v;
        lm = fmaxf(lm, v);
      }
      #pragma unroll
      for (int mk = 1; mk < 32; mk <<= 1) lm = fmaxf(lm, __shfl_xor(lm, mk, 64));
      float se = 0.f;
      #pragma unroll
      for (int ig = 0; ig < 16; ++ig) {
        float ev = __expf(S[qi][ig] - lm);
        S[qi][ig] = ev;
        se += ev;
      }
      #pragma unroll
      for (int mk = 1; mk < 32; mk <<= 1) se += __shfl_xor(se, mk, 64);
      float inv = 1.f / se;
      bf16* prow = P + (qbase + qi)*520;
      #pragma unroll
      for (int ig = 0; ig < 16; ++ig)
        prow[tx + 32*ig] = f2b(S[qi][ig]*inv);
    }

    int w = tid >> 6, l = tid & 63;
    int arow = l & 15, kgrp = l >> 4;
    facc4 acc = {0.f, 0.f, 0.f, 0.f};
    for (int kh = 0; kh < 2; ++kh) {
      __syncthreads();
      for (int i = tid; i < 2048; i += 256) {
        int m2 = (i & 127) << 1;
        int cc = (i >> 7) << 2;
        const bf16* gp = vvc + ((long)(lt*NN + kh*256 + m2))*128 + 64 + cc;
        ushort4 a = *(const ushort4*)(gp);
        ushort4 b = *(const ushort4*)(gp + 128);
        *(unsigned*)(vTh + (cc+0)*264 + m2) = (unsigned)a.x | ((unsigned)b.x << 16);
        *(unsigned*)(vTh + (cc+1)*264 + m2) = (unsigned)a.y | ((unsigned)b.y << 16);
        *(unsigned*)(vTh + (cc+2)*264 + m2) = (unsigned)a.z | ((unsigned)b.z << 16);
        *(unsigned*)(vTh + (cc+3)*264 + m2) = (unsigned)a.w | ((unsigned)b.w << 16);
      }
      __syncthreads();
      const bf16* pa = P + arow*520 + kh*256 + kgrp*8;
      const bf16* pb = vTh + (w*16 + arow)*264 + kgrp*8;
      #pragma unroll
      for (int ks = 0; ks < 8; ++ks) {
        bfrag8 av = *(const bfrag8*)(pa + ks*32);
        bfrag8 bv = *(const bfrag8*)(pb + ks*32);
        acc = __builtin_amdgcn_mfma_f32_16x16x32_bf16(av, bv, acc, 0, 0, 0);
      }
    }
    // sole writer of resid2 — plain stores, race-free vs dyn's resid +=
    long rb = ((long)gt*NN + qt*16)*64 + w*16 + arow;
    #pragma unroll
    for (int r = 0; r < 4; ++r) {
      int row = kgrp*4 + r;
      resid2[rb + (long)row*64] = acc[r];
    }
    return;
  }

  // ================= dynamic attention (h = yy) =================
  float* sc    = (float*)smem;                    // [16][520] (A)
  bf16*  vT    = (bf16*)smem;                     // [32][520] (B)
  float* kt    = (float*)(smem + 33280);          // [128][36] (A)
  bf16*  p_lds = (bf16*)(smem + 33280);           // [16][520] (B)
  float* red   = (float*)(smem + 49920);          // [2][272]
  float* ulds  = (float*)(smem + 51712);          // [16][8]
  float* means = (float*)(smem + 52224);          // [16]

  int h = yy;
  int qce = h*32, kce = 64 + h*32;

  float4 q0r[8], q1r[8];
  {
    const float* qp = qkx + ((long)(lt*NN + qt*16 + qbase))*128 + qce;
    #pragma unroll
    for (int j = 0; j < 8; ++j) q0r[j] = *(const float4*)(qp + j*4);
    #pragma unroll
    for (int j = 0; j < 8; ++j) q1r[j] = *(const float4*)(qp + 128 + j*4);
  }

  float S[2][16];
  for (int p = 0; p < 4; ++p) {
    __syncthreads();
    for (int i = tid; i < 1024; i += 256) {
      int row = i >> 3, jj = (i & 7) << 2;
      *(float4*)(kt + row*36 + jj) =
        *(const float4*)(qkx + ((long)(lt*NN + p*128 + row))*128 + kce + jj);
    }
    __syncthreads();
    #pragma unroll
    for (int ii = 0; ii < 4; ++ii) {
      int m = tx + 32*ii;
      const float4* kr4 = (const float4*)(kt + m*36);
      float4 k0 = kr4[0], k1 = kr4[1], k2 = kr4[2], k3 = kr4[3];
      float4 k4 = kr4[4], k5 = kr4[5], k6 = kr4[6], k7 = kr4[7];
      // numpy einsum baseline-SIMD emulation: 4 lanes, sequential unfused
      // mul+add per lane over d = l, l+4, ..., l+28; SSE3 hadd tree at end.
      {
        float v0 = 0.f, v1 = 0.f, v2 = 0.f, v3 = 0.f;
        MULADD4(q0r[0], k0); MULADD4(q0r[1], k1); MULADD4(q0r[2], k2); MULADD4(q0r[3], k3);
        MULADD4(q0r[4], k4); MULADD4(q0r[5], k5); MULADD4(q0r[6], k6); MULADD4(q0r[7], k7);
        float s = __fadd_rn(__fadd_rn(v0, v1), __fadd_rn(v2, v3));
        s = s * 0.125f;
        S[0][p*4+ii] = s;
        sc[(qbase+0)*520 + p*128 + m] = s;
      }
      {
        float v0 = 0.f, v1 = 0.f, v2 = 0.f, v3 = 0.f;
        MULADD4(q1r[0], k0); MULADD4(q1r[1], k1); MULADD4(q1r[2], k2); MULADD4(q1r[3], k3);
        MULADD4(q1r[4], k4); MULADD4(q1r[5], k5); MULADD4(q1r[6], k6); MULADD4(q1r[7], k7);
        float s = __fadd_rn(__fadd_rn(v0, v1), __fadd_rn(v2, v3));
        s = s * 0.125f;
        S[1][p*4+ii] = s;
        sc[(qbase+1)*520 + p*128 + m] = s;
      }
    }
  }
  __syncthreads();

  // ---- T14 async-stage split: issue V-tile global loads NOW (into registers);
  //      HBM latency hides under the mean + softmax below. LDS writes deferred.
  ushort4 vpa[8], vpb[8];
  #pragma unroll
  for (int j = 0; j < 8; ++j) {
    int i = tid + j*256;
    int m2 = (i & 255) << 1;
    int cc = (i >> 8) << 2;
    const bf16* gp = vvc + ((long)(lt*NN + m2))*128 + qce + cc;
    vpa[j] = *(const ushort4*)(gp);
    vpb[j] = *(const ushort4*)(gp + 128);
  }

  // numpy pairwise mean: 4 base-blocks of 128, 8 strided accumulators each
  if (tid < 128) {
    int row = tid >> 3, b = (tid >> 1) & 3, hh = tid & 1;
    const float* a = sc + row*520 + b*128 + hh*4;
    float4 r4 = *(const float4*)a;
    #pragma unroll
    for (int i = 8; i < 128; i += 8) {
      float4 v = *(const float4*)(a + i);
      r4.x = __fadd_rn(r4.x, v.x); r4.y = __fadd_rn(r4.y, v.y);
      r4.z = __fadd_rn(r4.z, v.z); r4.w = __fadd_rn(r4.w, v.w);
    }
    ulds[row*8 + b*2 + hh] = __fadd_rn(__fadd_rn(r4.x, r4.y), __fadd_rn(r4.z, r4.w));
  }
  __syncthreads();
  if (tid < 16) {
    const float* ur = ulds + tid*8;
    float p0 = __fadd_rn(ur[0], ur[1]);
    float p1 = __fadd_rn(ur[2], ur[3]);
    float p2 = __fadd_rn(ur[4], ur[5]);
    float p3 = __fadd_rn(ur[6], ur[7]);
    means[tid] = __fadd_rn(__fadd_rn(p0, p1), __fadd_rn(p2, p3)) * (1.f/512.f);
  }
  __syncthreads();   // all sc reads complete — vT (aliasing sc) may be written after this

  long obase = ((long)(gt*2 + h))*NN*NN;
  #pragma unroll
  for (int qi = 0; qi < 2; ++qi) {
    float mn = means[qbase + qi];
    unsigned kmask = 0; float lm = -INFINITY;
    #pragma unroll
    for (int ig = 0; ig < 16; ++ig) {
      if (S[qi][ig] >= mn) { kmask |= (1u << ig); lm = fmaxf(lm, S[qi][ig]); }
    }
    #pragma unroll
    for (int mk = 1; mk < 32; mk <<= 1) lm = fmaxf(lm, __shfl_xor(lm, mk, 64));
    float e[16]; float se = 0.f;
    #pragma unroll
    for (int ig = 0; ig < 16; ++ig) {
      e[ig] = ((kmask >> ig) & 1u) ? __expf(S[qi][ig] - lm) : 0.f;
      se += e[ig];
    }
    #pragma unroll
    for (int mk = 1; mk < 32; mk <<= 1) se += __shfl_xor(se, mk, 64);
    float inv = 1.f/se;
    float* rowp = attn_out + obase + (long)(qt*16 + qbase + qi)*NN;
    bf16* prow = p_lds + (qbase + qi)*520;
    #pragma unroll
    for (int ig = 0; ig < 16; ++ig) {
      float pr = e[ig]*inv;
      __builtin_nontemporal_store(pr, rowp + tx + 32*ig);   // write-once output
      prow[tx + 32*ig] = f2b(pr);
    }
  }

  // write prefetched V^T registers to LDS (same pack arithmetic as round 6)
  #pragma unroll
  for (int j = 0; j < 8; ++j) {
    int i = tid + j*256;
    int m2 = (i & 255) << 1;
    int cc = (i >> 8) << 2;
    *(unsigned*)(vT + (cc+0)*520 + m2) = (unsigned)vpa[j].x | ((unsigned)vpb[j].x << 16);
    *(unsigned*)(vT + (cc+1)*520 + m2) = (unsigned)vpa[j].y | ((unsigned)vpb[j].y << 16);
    *(unsigned*)(vT + (cc+2)*520 + m2) = (unsigned)vpa[j].z | ((unsigned)vpb[j].z << 16);
    *(unsigned*)(vT + (cc+3)*520 + m2) = (unsigned)vpa[j].w | ((unsigned)vpb[j].w << 16);
  }
  __syncthreads();

  {
    int w = tid >> 6, l = tid & 63;
    int nh = w & 1, kh = w >> 1;
    int arow = l & 15, kgrp = l >> 4;
    facc4 acc = {0.f, 0.f, 0.f, 0.f};
    const bf16* pa = p_lds + arow*520 + kh*256 + kgrp*8;
    const bf16* pb = vT + (nh*16 + arow)*520 + kh*256 + kgrp*8;
    #pragma unroll
    for (int ks = 0; ks < 8; ++ks) {
      bfrag8 av = *(const bfrag8*)(pa + ks*32);
      bfrag8 bv = *(const bfrag8*)(pb + ks*32);
      acc = __builtin_amdgcn_mfma_f32_16x16x32_bf16(av, bv, acc, 0, 0, 0);
    }
    if (w >= 2) {
      #pragma unroll
      for (int r = 0; r < 4; ++r)
        red[nh*272 + (kgrp*4 + r)*17 + arow] = acc[r];
    }
    __syncthreads();
    if (w < 2) {
      // dyn heads write disjoint column ranges (h*32..h*32+31) — race-free
      long rb = ((long)gt*NN + qt*16)*64 + h*32 + nh*16 + arow;
      #pragma unroll
      for (int r = 0; r < 4; ++r) {
        int row = kgrp*4 + r;
        resid[rb + (long)row*64] += acc[r] + red[nh*272 + row*17 + arow];
      }
    }
  }
}

// ---------------- LN1 fused into MLP gemm1 (reads resid + resid2) ----------------
__global__ __launch_bounds__(256) void k_mlp1(
  const float* __restrict__ resid, const float* __restrict__ resid2,
  const float* __restrict__ g1, const float* __restrict__ b1,
  const float* __restrict__ B, const float* __restrict__ bias, float* __restrict__ C)
{
  __shared__ float As[64][68];
  __shared__ float Bs[64][68];
  int rt = blockIdx.x, bcn = blockIdx.y;
  int tid = threadIdx.x;
  int tx = tid & 15, ty = tid >> 4;
  int wave = tid >> 6, lane = tid & 63;
  for (int rr = wave; rr < 64; rr += 4) {
    long idx = ((long)rt*64 + rr)*64 + lane;
    float v = resid[idx] + resid2[idx];   // (h+dyn)+st — round-4 association
    float m = wsum64(v)*(1.f/64.f);
    float d = v - m;
    float var = wsum64(d*d)*(1.f/64.f);
    As[lane][rr] = d*rsqrtf(var + 1e-5f)*g1[lane] + b1[lane];
  }
  #pragma unroll
  for (int i = 0; i < 4; ++i) {
    int t = i*256 + tid;
    int m = t >> 4, kq = (t & 15)*4;
    float4 bv = *(const float4*)&B[(long)(bcn*64 + m)*64 + kq];
    Bs[kq+0][m] = bv.x; Bs[kq+1][m] = bv.y; Bs[kq+2][m] = bv.z; Bs[kq+3][m] = bv.w;
  }
  __syncthreads();
  float acc[4][4] = {{0.f}};
  #pragma unroll 8
  for (int kk = 0; kk < 64; ++kk) {
    float4 a4 = *(const float4*)&As[kk][ty*4];
    float4 b4 = *(const float4*)&Bs[kk][tx*4];
    acc[0][0] += a4.x*b4.x; acc[0][1] += a4.x*b4.y; acc[0][2] += a4.x*b4.z; acc[0][3] += a4.x*b4.w;
    acc[1][0] += a4.y*b4.x; acc[1][1] += a4.y*b4.y; acc[1][2] += a4.y*b4.z; acc[1][3] += a4.y*b4.w;
    acc[2][0] += a4.z*b4.x; acc[2][1] += a4.z*b4.y; acc[2][2] += a4.z*b4.z; acc[2][3] += a4.z*b4.w;
    acc[3][0] += a4.w*b4.x; acc[3][1] += a4.w*b4.y; acc[3][2] += a4.w*b4.z; acc[3][3] += a4.w*b4.w;
  }
  #pragma unroll
  for (int i = 0; i < 4; ++i) {
    long ro = (long)(rt*64 + ty*4 + i)*128 + bcn*64 + tx*4;
    #pragma unroll
    for (int j = 0; j < 4; ++j) C[ro + j] = acc[i][j] + bias[bcn*64 + tx*4 + j];
  }
}

// ---------------- LN2 + leaky + PE fused into mha in-projection (resid + resid2) ----
__global__ __launch_bounds__(256) void k_mha_in(
  const float* __restrict__ mlpo, const float* __restrict__ resid,
  const float* __restrict__ resid2,
  const float* __restrict__ g2, const float* __restrict__ b2,
  const float* __restrict__ B, const float* __restrict__ bias, bf16* __restrict__ C)
{
  __shared__ float As[64][68];
  __shared__ float Bs[64][68];
  int rt = blockIdx.x, bcn = blockIdx.y;
  int tid = threadIdx.x;
  int tx = tid & 15, ty = tid >> 4;
  int wave = tid >> 6, lane = tid & 63;
  for (int rr = wave; rr < 64; rr += 4) {
    long r = (long)rt*64 + rr;
    float rf = resid[r*64 + lane] + resid2[r*64 + lane];  // == round-4 resid
    float v = mlpo[r*64 + lane] + rf;
    float m = wsum64(v)*(1.f/64.f);
    float d = v - m;
    float var = wsum64(d*d)*(1.f/64.f);
    float y = d*rsqrtf(var + 1e-5f)*g2[lane] + b2[lane];
    y = lk(y);
    float tf = (float)(r / NN);
    float dv = __expf(-(float)(lane & ~1) * 0.14391156831212787f);
    float pe = (lane & 1) ? cosf(tf*dv) : sinf(tf*dv);
    As[lane][rr] = y + pe;
  }
  #pragma unroll
  for (int i = 0; i < 4; ++i) {
    int t = i*256 + tid;
    int m = t >> 4, kq = (t & 15)*4;
    float4 bv = *(const float4*)&B[(long)(bcn*64 + m)*64 + kq];
    Bs[kq+0][m] = bv.x; Bs[kq+1][m] = bv.y; Bs[kq+2][m] = bv.z; Bs[kq+3][m] = bv.w;
  }
  __syncthreads();
  float acc[4][4] = {{0.f}};
  #pragma unroll 8
  for (int kk = 0; kk < 64; ++kk) {
    float4 a4 = *(const float4*)&As[kk][ty*4];
    float4 b4 = *(const float4*)&Bs[kk][tx*4];
    acc[0][0] += a4.x*b4.x; acc[0][1] += a4.x*b4.y; acc[0][2] += a4.x*b4.z; acc[0][3] += a4.x*b4.w;
    acc[1][0] += a4.y*b4.x; acc[1][1] += a4.y*b4.y; acc[1][2] += a4.y*b4.z; acc[1][3] += a4.y*b4.w;
    acc[2][0] += a4.z*b4.x; acc[2][1] += a4.z*b4.y; acc[2][2] += a4.z*b4.z; acc[2][3] += a4.z*b4.w;
    acc[3][0] += a4.w*b4.x; acc[3][1] += a4.w*b4.y; acc[3][2] += a4.w*b4.z; acc[3][3] += a4.w*b4.w;
  }
  #pragma unroll
  for (int i = 0; i < 4; ++i) {
    long ro = (long)(rt*64 + ty*4 + i)*192 + bcn*64 + tx*4;
    #pragma unroll
    for (int j = 0; j < 4; ++j) C[ro + j] = f2b(acc[i][j] + bias[bcn*64 + tx*4 + j]);
  }
}

// ---------------- head v2: 256 threads (4 waves) ----------------
// Scores: s strided across waves (per-s arithmetic identical). Softmax: wave 0
// only (bit-identical). PV + the three matvecs: 4 wave-partials combined on
// wave 0 (fp32 reorder on tolerant head path; weight loads float4, in-order
// fmaf within each partial). All barriers are full-block.
__global__ __launch_bounds__(256) void k_head(
  const bf16* __restrict__ mqkv, const float* __restrict__ rts,
  const float* __restrict__ mow, const float* __restrict__ mob,
  const float* __restrict__ xsw, const float* __restrict__ xtw, const float* __restrict__ xtb,
  const float* __restrict__ hw, const float* __restrict__ hb,
  const float* __restrict__ linw, const float* __restrict__ linb,
  float* __restrict__ out)
{
  int n = blockIdx.x;
  int tid = threadIdx.x, o = tid & 63, wv = tid >> 6;
  __shared__ float ps[TT];
  __shared__ float pacc[4][64];
  __shared__ float buf[64], buf2[64];

  // scores: wave wv handles s = wv, wv+4, ...
  float mq = b2f(mqkv[((long)(TT-1)*NN + n)*192 + o]);
  for (int s = wv; s < TT; s += 4) {
    float v = mq * b2f(mqkv[((long)s*NN + n)*192 + 64 + o]);
    v = wsum64(v);
    if (o == 0) ps[s] = v * SCALEV;
  }
  __syncthreads();
  // softmax over TT on wave 0 (same op order as before)
  if (wv == 0) {
    float x = (o < TT) ? ps[o] : -INFINITY;
    float mx = wmax64(x);
    float e = (o < TT) ? __expf(x - mx) : 0.f;
    float se = wsum64(e);
    if (o < TT) ps[o] = e / se;
  }
  __syncthreads();
  // PV: wave partials (tolerant fp32 reorder)
  {
    float p4 = 0.f;
    for (int s = wv; s < TT; s += 4)
      p4 += ps[s]*b2f(mqkv[((long)s*NN + n)*192 + 128 + o]);
    pacc[wv][o] = p4;
  }
  __syncthreads();
  if (wv == 0)
    buf[o] = (pacc[0][o] + pacc[1][o]) + (pacc[2][o] + pacc[3][o]);
  __syncthreads();
  // matvec 1: acc2 = mob + buf @ mow^T, k = wv*16..+16 per wave (float4 weights)
  {
    float pp = 0.f;
    const float* wrow = mow + (long)o*64 + wv*16;
    const float* bb = buf + wv*16;
    #pragma unroll
    for (int j = 0; j < 4; ++j) {
      float4 w = *(const float4*)(wrow + j*4);
      pp = fmaf(bb[j*4+0], w.x, pp);
      pp = fmaf(bb[j*4+1], w.y, pp);
      pp = fmaf(bb[j*4+2], w.z, pp);
      pp = fmaf(bb[j*4+3], w.w, pp);
    }
    pacc[wv][o] = pp;
  }
  __syncthreads();
  float a = 0.f, rt = 0.f;
  if (wv == 0) {
    float acc2 = mob[o] + ((pacc[0][o] + pacc[1][o]) + (pacc[2][o] + pacc[3][o]));
    float m2 = wsum64(acc2)*(1.f/64.f);
    float d2 = acc2 - m2;
    float var2 = wsum64(d2*d2)*(1.f/64.f);
    a = d2*rsqrtf(var2 + 1e-5f);
    rt = rts[(long)n*64 + o];
    buf[o] = a; buf2[o] = rt;
  }
  __syncthreads();
  // matvec 2: pre = xtb + buf@xsw^T + buf2@xtw^T
  {
    float pp = 0.f;
    const float* w1 = xsw + (long)o*64 + wv*16;
    const float* w2 = xtw + (long)o*64 + wv*16;
    const float* b1 = buf + wv*16;
    const float* b2p = buf2 + wv*16;
    #pragma unroll
    for (int j = 0; j < 4; ++j) {
      float4 wa = *(const float4*)(w1 + j*4);
      float4 wb = *(const float4*)(w2 + j*4);
      pp = fmaf(b1[j*4+0], wa.x, pp); pp = fmaf(b2p[j*4+0], wb.x, pp);
      pp = fmaf(b1[j*4+1], wa.y, pp); pp = fmaf(b2p[j*4+1], wb.y, pp);
      pp = fmaf(b1[j*4+2], wa.z, pp); pp = fmaf(b2p[j*4+2], wb.z, pp);
      pp = fmaf(b1[j*4+3], wa.w, pp); pp = fmaf(b2p[j*4+3], wb.w, pp);
    }
    pacc[wv][o] = pp;
  }
  __syncthreads();
  if (wv == 0) {
    float pre = xtb[o] + ((pacc[0][o] + pacc[1][o]) + (pacc[2][o] + pacc[3][o]));
    float zg = sgm(pre);
    float u = zg*a + (1.f - zg)*rt;
    buf[o] = u;
  }
  __syncthreads();
  // matvec 3: f = hb + buf @ hw^T
  {
    float pp = 0.f;
    const float* wrow = hw + (long)o*64 + wv*16;
    const float* bb = buf + wv*16;
    #pragma unroll
    for (int j = 0; j < 4; ++j) {
      float4 w = *(const float4*)(wrow + j*4);
      pp = fmaf(bb[j*4+0], w.x, pp);
      pp = fmaf(bb[j*4+1], w.y, pp);
      pp = fmaf(bb[j*4+2], w.z, pp);
      pp = fmaf(bb[j*4+3], w.w, pp);
    }
    pacc[wv][o] = pp;
  }
  __syncthreads();
  if (wv == 0) {
    float f = hb[o] + ((pacc[0][o] + pacc[1][o]) + (pacc[2][o] + pacc[3][o]));
    f = lk(f);
    float tot = wsum64(f * linw[o]);
    if (o == 0) out[n] = tot + linb[0];
  }
}

// =======================================================================
extern "C" void kernel_launch(void* const* d_in, const int* in_sizes, int n_in,
                              void* d_out, int out_size, void* d_ws, size_t ws_size,
                              hipStream_t stream)
{
  const float* x    = (const float*)d_in[0];
  const int*   ei   = (const int*)  d_in[1];
  const float* fcw  = (const float*)d_in[2];
  const float* fcb  = (const float*)d_in[3];
  const float* wih0 = (const float*)d_in[4];
  const float* whh0 = (const float*)d_in[5];
  const float* bih0 = (const float*)d_in[6];
  const float* bhh0 = (const float*)d_in[7];
  const float* wih1 = (const float*)d_in[8];
  const float* whh1 = (const float*)d_in[9];
  const float* bih1 = (const float*)d_in[10];
  const float* bhh1 = (const float*)d_in[11];
  const float* dmqw = (const float*)d_in[12];
  const float* dmkw = (const float*)d_in[13];
  const float* dmvw = (const float*)d_in[14];
  const float* dmvb = (const float*)d_in[15];
  const float* ssqw = (const float*)d_in[16];
  const float* sskw = (const float*)d_in[17];
  const float* ssvw = (const float*)d_in[18];
  const float* ssvb = (const float*)d_in[19];
  const float* ln1g = (const float*)d_in[20];
  const float* ln1b = (const float*)d_in[21];
  const float* ln2g = (const float*)d_in[22];
  const float* ln2b = (const float*)d_in[23];
  const float* mw1  = (const float*)d_in[24];
  const float* mb1  = (const float*)d_in[25];
  const float* mw2  = (const float*)d_in[26];
  const float* mb2  = (const float*)d_in[27];
  const float* mhw  = (const float*)d_in[28];
  const float* mhb  = (const float*)d_in[29];
  const float* mow  = (const float*)d_in[30];
  const float* mob  = (const float*)d_in[31];
  const float* gxsw = (const float*)d_in[32];
  const float* gxtw = (const float*)d_in[33];
  const float* gxtb = (const float*)d_in[34];
  const float* ghw  = (const float*)d_in[35];
  const float* ghb  = (const float*)d_in[36];
  const float* linw = (const float*)d_in[37];
  const float* linb = (const float*)d_in[38];

  // ---- workspace layout (~43.6 MB envelope) ----
  char* base = (char*)d_ws;
  float*  xs    = (float*)(base);                 // xs f32; later mlpo f32
  char*   Rb    = base + 7864320;                 // shared region (15.73 MB):
  float*  qkc   = (float*)Rb;                     //   per-chunk qs|ks f32 (5.24MB)
  bf16*   vvc   = (bf16*)(Rb + 5242880);          //   per-chunk v|vs bf16 (2.62MB)
  float*  qkx   = (float*)(Rb + 7864320);         //   per-chunk exact q|k f32 (5.24MB)
  float*  mlph  = (float*)Rb;                     //   later: mlp hidden f32
  bf16*   mqkv  = (bf16*)Rb;                      //   later: mha qkv bf16
  bf16*   g0    = (bf16*)(base + 23592960);
  float*  resid = (float*)(base + 27525120);      // h + dyn
  float*  resid2= (float*)(base + 35389440);      // static-attn contribution (7.86MB)
  float*  rts   = (float*)(base + 43253760);
  unsigned int* msk = (unsigned int*)(base + 43384832);
  float*  Wall  = (float*)(base + 43417600);      // 6*4096 f32 (q|k|qs|ks|v|vs)
  float*  bcV   = (float*)(base + 43515904);      // 128 f32
  float*  mlpo  = xs;
  float*  outb  = (float*)d_out;
  float*  attn  = outb + 512;
  // gi staged in d_out's attn region — dead before k_attn writes probs
  float*  gi    = (float*)((char*)d_out + 2048);

  k_pack<<<dim3(98), 256, 0, stream>>>(dmqw, dmkw, ssqw, sskw, dmvw, ssvw, dmvb, ssvb, ei, msk, Wall, bcV);
  k_fcin<<<dim3(TN*64/256), 256, 0, stream>>>(x, fcw, fcb, xs, resid);
  // GRU layer 0
  k_gemm<float,float><<<dim3(480, 3), 256, 0, stream>>>(xs, wih0, bih0, gi, 64, 192, 1);
  k_gru<<<dim3(NN), 192, 0, stream>>>(gi, whh0, bhh0, g0, nullptr, 0);
  // GRU layer 1
  k_gemm<bf16,float><<<dim3(480, 3), 256, 0, stream>>>(g0, wih1, bih1, gi, 64, 192, 1);
  k_gru<<<dim3(NN), 192, 0, stream>>>(gi, whh1, bhh1, nullptr, rts, 1);
  // attention in 3 t-chunks of 20 (dyn + static merged, XCD-swizzled 1D grid)
  for (int tc = 0; tc < NCHK; ++tc) {
    const float* xsc = xs + (size_t)tc*TCH*NN*64;
    k_proj<<<dim3(TCH*NN/64, 6), 256, 0, stream>>>(xsc, Wall, bcV, qkx, qkc, vvc);
    k_attn<<<dim3(1920), 256, 0, stream>>>(qkx, qkc, vvc, msk, attn, resid, resid2, tc);
  }
  // LN1+MLP1 -> MLP2 -> LN2+PE+mha-in -> head
  k_mlp1<<<dim3(480, 2), 256, 0, stream>>>(resid, resid2, ln1g, ln1b, mw1, mb1, mlph);
  k_gemm<float,float><<<dim3(480, 1), 256, 0, stream>>>(mlph, mw2, mb2, mlpo, 128, 64, 0);
  k_mha_in<<<dim3(480, 3), 256, 0, stream>>>(mlpo, resid, resid2, ln2g, ln2b, mhw, mhb, mqkv);
  k_head<<<dim3(NN), 256, 0, stream>>>(mqkv, rts, mow, mob, gxsw, gxtw, gxtb, ghw, ghb, linw, linb, outb);
}